// Round 11
// baseline (1973.820 us; speedup 1.0000x reference)
//
#include <hip/hip_runtime.h>
#include <hip/hip_bf16.h>
#include <stdint.h>
#include <type_traits>

typedef __hip_bfloat16 bf16;
typedef __attribute__((ext_vector_type(8))) short bf16x8;
typedef __attribute__((ext_vector_type(4))) float f32x4;

#define DMODEL 512
#define HFF    2048
#define NHEADS 8
#define NLAYERS 6
#define DHEAD  64
#define BATCH  256
#define SXLEN  15
#define SYLEN  17

__device__ __forceinline__ float us2f(unsigned short u) {
  union { unsigned int i; float f; } c; c.i = ((unsigned int)u) << 16; return c.f;
}
__device__ __forceinline__ unsigned short f2us(float f) {
  bf16 h = __float2bfloat16(f);
  return *reinterpret_cast<unsigned short*>(&h);
}
__device__ __forceinline__ float b2f(bf16 v) { return __bfloat162float(v); }

__device__ __forceinline__ void gload_lds16(const void* g, void* l) {
  __builtin_amdgcn_global_load_lds(
      (const __attribute__((address_space(1))) unsigned int*)g,
      (__attribute__((address_space(3))) unsigned int*)l, 16, 0, 0);
}

// ---------------- generic bf16 GEMM: C = A[M,ldk] @ Wt[N,ldk]^T (+bias, opt ReLU)
// Wt = transposed bf16 weight ([N,K] row-major, row stride ldk). bias f32.
// Tile MT x NT, wave grid WM x WN, BK=64, XOR-swizzled LDS (both sides).
// DBUF=1: double-buffered LDS, prefetch next K-tile before compute, ONE barrier
// per K-step (guide T3 minimal 2-phase). DBUF=0: classic 2-barrier loop.
// ZMAP=0: linear z strides. ZMAP=1: cross-KV map (z -> layer z/2, mat 5+z%2).
// ZMAP=2: split-K (z selects k-chunk of length K; C offset by cStride).
template<int RELU, int MT, int NT, int WM, int WN, int ZMAP, int BIAS, int DBUF, typename OT>
__global__ __launch_bounds__(WM * WN * 64) void gemm_t(
    const bf16* __restrict__ A, const bf16* __restrict__ Wt,
    const float* __restrict__ bias, OT* __restrict__ C,
    int M, int N, int K, int ldk,
    long long wStride, long long bStride, long long cStride)
{
  constexpr int BK  = 64;
  constexpr int TH  = WM * WN * 64;
  constexpr int RB  = BK * 2;         // 128B LDS rows
  constexpr int MF  = MT / WM / 16;
  constexpr int NF  = NT / WN / 16;
  constexpr int WRS = MT / WM;
  constexpr int WCS = NT / WN;
  constexpr int ABY = MT * RB;
  constexpr int BBY = NT * RB;
  constexpr int BUFBY = ABY + BBY;

  const int z = blockIdx.z;
  long long koff = 0;
  if (ZMAP == 1) {
    int idx = (z >> 1) * 8 + 5 + (z & 1);
    Wt   += (long long)idx * wStride;
    bias += (long long)idx * bStride;
  } else if (ZMAP == 2) {
    koff = (long long)z * K;
  } else {
    Wt   += (long long)z * wStride;
    bias += (long long)z * bStride;
  }
  C += (long long)z * cStride;

  __shared__ __align__(16) char lds[(DBUF ? 2 : 1) * BUFBY];
  const int t    = threadIdx.x;
  const int m0   = blockIdx.y * MT, n0 = blockIdx.x * NT;
  const int wid  = t >> 6, lane = t & 63;
  const int wm   = wid / WN, wn = wid % WN;
  const int g    = lane >> 4, r = lane & 15;

  f32x4 acc[MF][NF];
  #pragma unroll
  for (int i = 0; i < MF; ++i)
    #pragma unroll
    for (int j = 0; j < NF; ++j) acc[i][j] = (f32x4)0.f;

  const char* Ab = (const char*)(A  + (long long)m0 * ldk + koff);
  const char* Bb = (const char*)(Wt + (long long)n0 * ldk + koff);
  const int rowBytes = ldk * 2;
  const int rdsw = (r & 7) << 4;      // read-side swizzle

  // staging helper (swizzled source, linear LDS dest)
  auto stage = [&](char* dst, int kt) {
    #pragma unroll
    for (int off = 0; off < ABY; off += TH * 16) {
      int o = off + t * 16;
      int row = o >> 7, cb = (o & 127) ^ ((row & 7) << 4);
      gload_lds16(Ab + (long long)row * rowBytes + kt * 2 + cb, dst + o);
    }
    #pragma unroll
    for (int off = 0; off < BBY; off += TH * 16) {
      int o = off + t * 16;
      int row = o >> 7, cb = (o & 127) ^ ((row & 7) << 4);
      gload_lds16(Bb + (long long)row * rowBytes + kt * 2 + cb, dst + ABY + o);
    }
  };
  auto compute = [&](const char* buf) {
    #pragma unroll
    for (int kh = 0; kh < BK / 32; ++kh) {
      bf16x8 af[MF], bfr[NF];
      #pragma unroll
      for (int ms = 0; ms < MF; ++ms)
        af[ms] = *(const bf16x8*)(buf + (wm * WRS + ms * 16 + r) * RB + ((kh * 64 + g * 16) ^ rdsw));
      #pragma unroll
      for (int ns = 0; ns < NF; ++ns)
        bfr[ns] = *(const bf16x8*)(buf + ABY + (wn * WCS + ns * 16 + r) * RB + ((kh * 64 + g * 16) ^ rdsw));
      #pragma unroll
      for (int ms = 0; ms < MF; ++ms)
        #pragma unroll
        for (int ns = 0; ns < NF; ++ns)
          acc[ms][ns] = __builtin_amdgcn_mfma_f32_16x16x32_bf16(af[ms], bfr[ns], acc[ms][ns], 0, 0, 0);
    }
  };

  if constexpr (DBUF) {
    // ---- 2-phase double-buffered: prefetch-next, single barrier per K-step ----
    const int nt = K / BK;
    stage(lds, 0);
    __syncthreads();                       // drains vmcnt -> buf0 ready
    int cur = 0;
    for (int tst = 0; tst < nt; ++tst) {
      if (tst + 1 < nt) stage(lds + (cur ^ 1) * BUFBY, (tst + 1) * BK);
      compute(lds + cur * BUFBY);
      __syncthreads();                     // drains prefetch + LDS reads
      cur ^= 1;
    }
  } else {
    for (int kt = 0; kt < K; kt += BK) {
      __syncthreads();
      stage(lds, kt);
      __syncthreads();
      compute(lds);
    }
  }

  // epilogue: C row = g*4+j, col = r (verified gfx950 16x16 C layout)
  #pragma unroll
  for (int ms = 0; ms < MF; ++ms) {
    int rowb = m0 + wm * WRS + ms * 16 + g * 4;
    #pragma unroll
    for (int ns = 0; ns < NF; ++ns) {
      int col = n0 + wn * WCS + ns * 16 + r;
      float bv = BIAS ? bias[col] : 0.f;
      f32x4 v = acc[ms][ns];
      #pragma unroll
      for (int j = 0; j < 4; ++j) {
        float o = v[j] + bv;
        if (RELU) o = fmaxf(o, 0.f);
        if constexpr (std::is_same<OT, float>::value)
          C[(long long)(rowb + j) * N + col] = o;
        else
          C[(long long)(rowb + j) * N + col] = __float2bfloat16(o);
      }
    }
  }
}

// ------------- batched transpose + cast: out[N,K](bf16) = in[K,N](f32) ---------
__global__ __launch_bounds__(256) void transpose_cast2(
    const float* __restrict__ inA, const float* __restrict__ inB, int zSplit,
    bf16* __restrict__ out, int K, int N)
{
  __shared__ unsigned short tile[32][33];
  int z = blockIdx.z;
  const float* ip = (z < zSplit) ? inA + (long long)z * K * N
                                 : inB + (long long)(z - zSplit) * K * N;
  unsigned short* op = (unsigned short*)out + (long long)z * K * N;
  int nx = blockIdx.x * 32, ky = blockIdx.y * 32;
  int tx = threadIdx.x, ty = threadIdx.y;   // (32,8)
  #pragma unroll
  for (int j = 0; j < 4; ++j)
    tile[ty + j * 8][tx] = f2us(ip[(long long)(ky + ty + j * 8) * N + nx + tx]);
  __syncthreads();
  #pragma unroll
  for (int j = 0; j < 4; ++j)
    op[(long long)(nx + ty + j * 8) * K + ky + tx] = tile[tx][ty + j * 8];
}

// ------------- embeddings (f32 tables) + sinusoidal PE -> bf16, both sides -----
__global__ __launch_bounds__(64) void embed2_k(
    const int* __restrict__ xids, const int* __restrict__ yids,
    const float* __restrict__ ex, const float* __restrict__ ey,
    bf16* __restrict__ ox, bf16* __restrict__ oy)
{
  int row = blockIdx.x;
  const int* ids; const float* emb; bf16* out; int S;
  if (row < BATCH * SXLEN) { ids = xids; emb = ex; out = ox; S = SXLEN; }
  else { row -= BATCH * SXLEN; ids = yids; emb = ey; out = oy; S = SYLEN; }
  int s = row % S;
  int lane = threadIdx.x;
  int id = ids[row];
  const float* e = emb + (long long)id * DMODEL;
  unsigned short* o = (unsigned short*)(out + (long long)row * DMODEL);
  #pragma unroll
  for (int j = 0; j < 8; ++j) {
    int d  = lane * 8 + j;
    int jj = d >> 1;
    float freq = __expf(-(float)(2 * jj) * (9.210340371976184f / 512.f)); // 10000^(-2j/512)
    float ang  = (float)s * freq;
    float pe   = (d & 1) ? cosf(ang) : sinf(ang);
    o[d] = f2us(e[d] + pe);
  }
}

// ---------------- attention core (one block per (b,h)) -------------------------
template<int CAUSAL>
__global__ __launch_bounds__(64) void attn_core(
    const bf16* __restrict__ Q, const bf16* __restrict__ Kk, const bf16* __restrict__ V,
    const int* __restrict__ tok, bf16* __restrict__ O, int Sq, int Sk)
{
  int bh = blockIdx.x; int b = bh >> 3; int h = bh & 7;
  __shared__ float Qs[SYLEN][DHEAD + 1], Ks[SYLEN][DHEAD + 1], Vs[SYLEN][DHEAD + 1];
  __shared__ float P[SYLEN][SYLEN + 1];
  __shared__ float msk[SYLEN];
  int t = threadIdx.x;

  for (int idx = t; idx < Sq * DHEAD; idx += 64) {
    int q = idx >> 6, d = idx & 63;
    Qs[q][d] = b2f(Q[((long long)(b * Sq + q)) * DMODEL + h * DHEAD + d]);
  }
  for (int idx = t; idx < Sk * DHEAD; idx += 64) {
    int k = idx >> 6, d = idx & 63;
    Ks[k][d] = b2f(Kk[((long long)(b * Sk + k)) * DMODEL + h * DHEAD + d]);
    Vs[k][d] = b2f(V [((long long)(b * Sk + k)) * DMODEL + h * DHEAD + d]);
  }
  if (t < Sk) msk[t] = (tok[b * Sk + t] != 0) ? 1.f : 0.f;
  __syncthreads();

  for (int idx = t; idx < Sq * Sk; idx += 64) {
    int q = idx / Sk, k = idx - q * Sk;
    float s = 0.f;
    #pragma unroll
    for (int i = 0; i < DHEAD; ++i) s += Qs[q][i] * Ks[k][i];
    s *= 0.125f;                       // 1/sqrt(64)
    bool m = (msk[k] != 0.f) && (!CAUSAL || k <= q);
    P[q][k] = m ? s : -1e9f;
  }
  __syncthreads();

  if (t < Sq) {
    float mx = -1e30f;
    for (int k = 0; k < Sk; ++k) mx = fmaxf(mx, P[t][k]);
    float sum = 0.f;
    for (int k = 0; k < Sk; ++k) { float e = __expf(P[t][k] - mx); P[t][k] = e; sum += e; }
    float inv = 1.f / sum;
    for (int k = 0; k < Sk; ++k) P[t][k] *= inv;
  }
  __syncthreads();

  int d = t;   // 64 lanes = 64 head dims
  for (int q = 0; q < Sq; ++q) {
    float o = 0.f;
    for (int k = 0; k < Sk; ++k) o += P[q][k] * Vs[k][d];
    O[((long long)(b * Sq + q)) * DMODEL + h * DHEAD + d] = __float2bfloat16(o);
  }
}

// ---- out = LN(R + P0 + P1 + bias) for split-K f32 partials, 1 wave/row --------
__global__ __launch_bounds__(64) void add_ln3_k(
    const bf16* __restrict__ R, const float* __restrict__ P, long long pStride,
    const float* __restrict__ bias,
    const float* __restrict__ gam, const float* __restrict__ bet,
    bf16* __restrict__ out)
{
  long long row = blockIdx.x;
  int lane = threadIdx.x;
  union { uint4 u; unsigned short s[8]; } ua, uo;
  ua.u = ((const uint4*)(R + row * DMODEL))[lane];
  const float4* p0 = (const float4*)(P + row * DMODEL);
  const float4* p1 = (const float4*)(P + pStride + row * DMODEL);
  float4 a0 = p0[lane * 2], a1 = p0[lane * 2 + 1];
  float4 c0 = p1[lane * 2], c1 = p1[lane * 2 + 1];
  float4 bi0 = ((const float4*)bias)[lane * 2], bi1 = ((const float4*)bias)[lane * 2 + 1];
  float pa[8] = {a0.x, a0.y, a0.z, a0.w, a1.x, a1.y, a1.z, a1.w};
  float pc[8] = {c0.x, c0.y, c0.z, c0.w, c1.x, c1.y, c1.z, c1.w};
  float pb[8] = {bi0.x, bi0.y, bi0.z, bi0.w, bi1.x, bi1.y, bi1.z, bi1.w};
  float x[8]; float s = 0.f, sq = 0.f;
  #pragma unroll
  for (int j = 0; j < 8; ++j) {
    x[j] = us2f(ua.s[j]) + pa[j] + pc[j] + pb[j];
    s += x[j]; sq += x[j] * x[j];
  }
  #pragma unroll
  for (int o = 32; o > 0; o >>= 1) { s += __shfl_xor(s, o); sq += __shfl_xor(sq, o); }
  float mean = s * (1.f / DMODEL);
  float var  = sq * (1.f / DMODEL) - mean * mean;
  float inv  = rsqrtf(var + 1e-5f);
  float4 g0 = ((const float4*)gam)[lane * 2], g1 = ((const float4*)gam)[lane * 2 + 1];
  float4 b0 = ((const float4*)bet)[lane * 2], b1 = ((const float4*)bet)[lane * 2 + 1];
  float gg[8] = {g0.x, g0.y, g0.z, g0.w, g1.x, g1.y, g1.z, g1.w};
  float bb[8] = {b0.x, b0.y, b0.z, b0.w, b1.x, b1.y, b1.z, b1.w};
  #pragma unroll
  for (int j = 0; j < 8; ++j)
    uo.s[j] = f2us(gg[j] * (x[j] - mean) * inv + bb[j]);
  ((uint4*)(out + row * DMODEL))[lane] = uo.u;
}

// ================================================================================
extern "C" void kernel_launch(void* const* d_in, const int* in_sizes, int n_in,
                              void* d_out, int out_size, void* d_ws, size_t ws_size,
                              hipStream_t stream)
{
  const int*   x        = (const int*)  d_in[0];
  const int*   y        = (const int*)  d_in[1];
  const float* emb_x    = (const float*)d_in[2];
  const float* emb_y    = (const float*)d_in[3];
  const float* enc_attn_w = (const float*)d_in[4];
  const float* enc_attn_b = (const float*)d_in[5];
  const float* enc_ln     = (const float*)d_in[6];
  const float* enc_f0w    = (const float*)d_in[7];
  const float* enc_f0b    = (const float*)d_in[8];
  const float* enc_f1w    = (const float*)d_in[9];
  const float* enc_f1b    = (const float*)d_in[10];
  const float* dec_attn_w = (const float*)d_in[11];
  const float* dec_attn_b = (const float*)d_in[12];
  const float* dec_ln     = (const float*)d_in[13];
  const float* dec_f0w    = (const float*)d_in[14];
  const float* dec_f0b    = (const float*)d_in[15];
  const float* dec_f1w    = (const float*)d_in[16];
  const float* dec_f1b    = (const float*)d_in[17];
  const float* fc_w       = (const float*)d_in[18];
  const float* fc_b       = (const float*)d_in[19];

  const int MX = BATCH * SXLEN;              // 3840
  const int MY = BATCH * SYLEN;              // 4352
  const long long DD = (long long)DMODEL * DMODEL;
  const long long SMEL = (long long)MY * DMODEL;
  const long long MXEL = (long long)MX * DMODEL;
  const long long FFEL = (long long)DMODEL * HFF;
  const long long PST  = (long long)MY * DMODEL;   // split-K partial stride

  // ---- workspace carve ----
  char* p = (char*)d_ws;
  auto alloc = [&](long long elems) -> bf16* {
    bf16* r = (bf16*)p; p += ((elems * 2 + 255) / 256) * 256; return r;
  };
  bf16* wt_attn = alloc(72 * DD);
  bf16* wt_f0   = alloc(12 * FFEL);
  bf16* wt_f1   = alloc(12 * FFEL);
  bf16* wt_fc   = alloc(32000LL * DMODEL);
  bf16* hx  = alloc(SMEL);
  bf16* hy  = alloc(SMEL);
  bf16* qb  = alloc(3 * SMEL);
  bf16* ao  = alloc(SMEL);
  bf16* h0  = alloc(SMEL);
  bf16* h1  = alloc(SMEL);
  bf16* mid = alloc((long long)MY * HFF);
  bf16* ckv = alloc(12 * MXEL);
  float* fp = (float*)alloc(2LL * MY * DMODEL * 2);  // 2 f32 split-K partials
  if ((size_t)(p - (char*)d_ws) > ws_size) return;

  bf16* wt_enc_attn = wt_attn;
  bf16* wt_dec_attn = wt_attn + 24 * DD;
  bf16* wt_enc_f0   = wt_f0;
  bf16* wt_dec_f0   = wt_f0 + 6 * FFEL;
  bf16* wt_enc_f1   = wt_f1;
  bf16* wt_dec_f1   = wt_f1 + 6 * FFEL;

  dim3 tb(32, 8);
  transpose_cast2<<<dim3(16, 16, 72), tb, 0, stream>>>(enc_attn_w, dec_attn_w, 24, wt_attn, DMODEL, DMODEL);
  transpose_cast2<<<dim3(64, 16, 12), tb, 0, stream>>>(enc_f0w, dec_f0w, 6, wt_f0, DMODEL, HFF);
  transpose_cast2<<<dim3(16, 64, 12), tb, 0, stream>>>(enc_f1w, dec_f1w, 6, wt_f1, HFF, DMODEL);
  transpose_cast2<<<dim3(1000, 16, 1), tb, 0, stream>>>(fc_w, fc_w, 1, wt_fc, DMODEL, 32000);

  embed2_k<<<MX + MY, 64, 0, stream>>>(x, y, emb_x, emb_y, hx, hy);

  // ---- encoder ----
  for (int i = 0; i < NLAYERS; ++i) {
    const bf16*  Wl = wt_enc_attn + (long long)i * 4 * DD;
    const float* Bl = enc_attn_b + (long long)i * 4 * DMODEL;
    const float* Lg = enc_ln + (size_t)i * 2048;
    gemm_t<0, 64, 64, 2, 1, 0, 1, 1, bf16><<<dim3(8, 60, 3), 128, 0, stream>>>(hx, Wl, Bl, qb,
        MX, DMODEL, DMODEL, DMODEL, DD, DMODEL, SMEL);
    attn_core<0><<<BATCH * NHEADS, 64, 0, stream>>>(qb, qb + SMEL, qb + 2 * SMEL, x, ao, SXLEN, SXLEN);
    // O-proj as split-K=2 -> f32 partials, then LN with residual
    gemm_t<0, 64, 64, 2, 1, 2, 0, 1, float><<<dim3(8, 60, 2), 128, 0, stream>>>(ao,
        Wl + 3 * DD, Bl + 3 * DMODEL, fp, MX, DMODEL, 256, DMODEL, 0, 0, PST);
    add_ln3_k<<<MX, 64, 0, stream>>>(hx, fp, PST, Bl + 3 * DMODEL, Lg, Lg + 512, h0);
    gemm_t<1, 128, 128, 2, 2, 0, 1, 0, bf16><<<dim3(16, 30, 1), 256, 0, stream>>>(h0,
        wt_enc_f0 + (long long)i * FFEL, enc_f0b + (long long)i * HFF, mid,
        MX, HFF, DMODEL, DMODEL, 0, 0, 0);
    gemm_t<0, 64, 64, 2, 1, 2, 0, 1, float><<<dim3(8, 60, 2), 128, 0, stream>>>(mid,
        wt_enc_f1 + (long long)i * FFEL, enc_f1b, fp,
        MX, DMODEL, 1024, HFF, 0, 0, PST);
    add_ln3_k<<<MX, 64, 0, stream>>>(h0, fp, PST,
        enc_f1b + (long long)i * DMODEL, Lg + 1024, Lg + 1536, hx);
  }

  // ---- all 6 decoder layers' cross K/V in one z=12 launch ----
  gemm_t<0, 64, 64, 2, 1, 1, 1, 1, bf16><<<dim3(8, 60, 12), 128, 0, stream>>>(hx, wt_dec_attn,
      dec_attn_b, ckv, MX, DMODEL, DMODEL, DMODEL, DD, DMODEL, MXEL);

  // ---- decoder ----
  for (int i = 0; i < NLAYERS; ++i) {
    const bf16*  Wl = wt_dec_attn + (long long)i * 8 * DD;
    const float* Bl = dec_attn_b + (long long)i * 8 * DMODEL;
    const float* Lg = dec_ln + (size_t)i * 3072;
    // self-attention
    gemm_t<0, 64, 64, 2, 1, 0, 1, 1, bf16><<<dim3(8, 68, 3), 128, 0, stream>>>(hy, Wl, Bl, qb,
        MY, DMODEL, DMODEL, DMODEL, DD, DMODEL, SMEL);
    attn_core<1><<<BATCH * NHEADS, 64, 0, stream>>>(qb, qb + SMEL, qb + 2 * SMEL, y, ao, SYLEN, SYLEN);
    gemm_t<0, 64, 64, 2, 1, 2, 0, 1, float><<<dim3(8, 68, 2), 128, 0, stream>>>(ao,
        Wl + 3 * DD, Bl + 3 * DMODEL, fp, MY, DMODEL, 256, DMODEL, 0, 0, PST);
    add_ln3_k<<<MY, 64, 0, stream>>>(hy, fp, PST, Bl + 3 * DMODEL, Lg, Lg + 512, h0);
    // cross-attention: q from h0; k/v precomputed in ckv
    gemm_t<0, 64, 64, 2, 1, 0, 1, 1, bf16><<<dim3(8, 68, 1), 128, 0, stream>>>(h0, Wl + 4 * DD, Bl + 4 * DMODEL, qb,
        MY, DMODEL, DMODEL, DMODEL, 0, 0, 0);
    attn_core<0><<<BATCH * NHEADS, 64, 0, stream>>>(qb, ckv + (long long)(2 * i) * MXEL,
        ckv + (long long)(2 * i + 1) * MXEL, x, ao, SYLEN, SXLEN);
    gemm_t<0, 64, 64, 2, 1, 2, 0, 1, float><<<dim3(8, 68, 2), 128, 0, stream>>>(ao,
        Wl + 7 * DD, Bl + 7 * DMODEL, fp, MY, DMODEL, 256, DMODEL, 0, 0, PST);
    add_ln3_k<<<MY, 64, 0, stream>>>(h0, fp, PST, Bl + 7 * DMODEL, Lg + 1024, Lg + 1536, h0);
    // FFN
    gemm_t<1, 128, 128, 2, 2, 0, 1, 0, bf16><<<dim3(16, 34, 1), 256, 0, stream>>>(h0,
        wt_dec_f0 + (long long)i * FFEL, dec_f0b + (long long)i * HFF, mid,
        MY, HFF, DMODEL, DMODEL, 0, 0, 0);
    gemm_t<0, 64, 64, 2, 1, 2, 0, 1, float><<<dim3(8, 68, 2), 128, 0, stream>>>(mid,
        wt_dec_f1 + (long long)i * FFEL, dec_f1b, fp,
        MY, DMODEL, 1024, HFF, 0, 0, PST);
    add_ln3_k<<<MY, 64, 0, stream>>>(h0, fp, PST,
        dec_f1b + (long long)i * DMODEL, Lg + 2048, Lg + 2560, hy);
  }

  // ---- final vocab projection (f32 out, 256x256 tile, 8 waves) ----
  gemm_t<0, 256, 256, 4, 2, 0, 1, 0, float><<<dim3(125, 17, 1), 512, 0, stream>>>(hy, wt_fc, fc_b,
      (float*)d_out, MY, 32000, DMODEL, DMODEL, 0, 0, 0);
}

// Round 12
// 1936.940 us; speedup vs baseline: 1.0190x; 1.0190x over previous
//
#include <hip/hip_runtime.h>
#include <hip/hip_bf16.h>
#include <stdint.h>
#include <type_traits>

typedef __hip_bfloat16 bf16;
typedef __attribute__((ext_vector_type(8))) short bf16x8;
typedef __attribute__((ext_vector_type(4))) float f32x4;

#define DMODEL 512
#define HFF    2048
#define NHEADS 8
#define NLAYERS 6
#define DHEAD  64
#define BATCH  256
#define SXLEN  15
#define SYLEN  17

__device__ __forceinline__ float us2f(unsigned short u) {
  union { unsigned int i; float f; } c; c.i = ((unsigned int)u) << 16; return c.f;
}
__device__ __forceinline__ unsigned short f2us(float f) {
  bf16 h = __float2bfloat16(f);
  return *reinterpret_cast<unsigned short*>(&h);
}
__device__ __forceinline__ float b2f(bf16 v) { return __bfloat162float(v); }

__device__ __forceinline__ void gload_lds16(const void* g, void* l) {
  __builtin_amdgcn_global_load_lds(
      (const __attribute__((address_space(1))) unsigned int*)g,
      (__attribute__((address_space(3))) unsigned int*)l, 16, 0, 0);
}

// ---------------- generic bf16 GEMM: C = A[M,ldk] @ Wt[N,ldk]^T (+bias, opt ReLU)
// Wt = transposed bf16 weight ([N,K] row-major, row stride ldk). bias f32.
// Tile MT x NT, wave grid WM x WN, BK=64, XOR-swizzled LDS (both sides).
// ZMAP=0: linear z strides. ZMAP=1: cross-KV map (z -> layer z/2, mat 5+z%2).
// ZMAP=2: split-K (z selects k-chunk of length K; C offset by cStride).
template<int RELU, int MT, int NT, int WM, int WN, int ZMAP, int BIAS, typename OT>
__global__ __launch_bounds__(WM * WN * 64) void gemm_t(
    const bf16* __restrict__ A, const bf16* __restrict__ Wt,
    const float* __restrict__ bias, OT* __restrict__ C,
    int M, int N, int K, int ldk,
    long long wStride, long long bStride, long long cStride)
{
  constexpr int BK  = 64;
  constexpr int TH  = WM * WN * 64;
  constexpr int RB  = BK * 2;         // 128B LDS rows
  constexpr int MF  = MT / WM / 16;
  constexpr int NF  = NT / WN / 16;
  constexpr int WRS = MT / WM;
  constexpr int WCS = NT / WN;
  constexpr int ABY = MT * RB;
  constexpr int BBY = NT * RB;

  const int z = blockIdx.z;
  long long koff = 0;
  if (ZMAP == 1) {
    int idx = (z >> 1) * 8 + 5 + (z & 1);
    Wt   += (long long)idx * wStride;
    bias += (long long)idx * bStride;
  } else if (ZMAP == 2) {
    koff = (long long)z * K;
  } else {
    Wt   += (long long)z * wStride;
    bias += (long long)z * bStride;
  }
  C += (long long)z * cStride;

  __shared__ __align__(16) char lds[ABY + BBY];
  const int t    = threadIdx.x;
  const int m0   = blockIdx.y * MT, n0 = blockIdx.x * NT;
  const int wid  = t >> 6, lane = t & 63;
  const int wm   = wid / WN, wn = wid % WN;
  const int g    = lane >> 4, r = lane & 15;

  f32x4 acc[MF][NF];
  #pragma unroll
  for (int i = 0; i < MF; ++i)
    #pragma unroll
    for (int j = 0; j < NF; ++j) acc[i][j] = (f32x4)0.f;

  const char* Ab = (const char*)(A  + (long long)m0 * ldk + koff);
  const char* Bb = (const char*)(Wt + (long long)n0 * ldk + koff);
  const int rowBytes = ldk * 2;
  const int rdsw = (r & 7) << 4;      // read-side swizzle

  for (int kt = 0; kt < K; kt += BK) {
    __syncthreads();
    #pragma unroll
    for (int off = 0; off < ABY; off += TH * 16) {
      int o = off + t * 16;
      int row = o >> 7, cb = (o & 127) ^ ((row & 7) << 4);   // pre-swizzled source
      gload_lds16(Ab + (long long)row * rowBytes + kt * 2 + cb, lds + o);
    }
    #pragma unroll
    for (int off = 0; off < BBY; off += TH * 16) {
      int o = off + t * 16;
      int row = o >> 7, cb = (o & 127) ^ ((row & 7) << 4);
      gload_lds16(Bb + (long long)row * rowBytes + kt * 2 + cb, lds + ABY + o);
    }
    __syncthreads();

    #pragma unroll
    for (int kh = 0; kh < BK / 32; ++kh) {
      bf16x8 af[MF], bfr[NF];
      #pragma unroll
      for (int ms = 0; ms < MF; ++ms)
        af[ms] = *(const bf16x8*)(lds + (wm * WRS + ms * 16 + r) * RB + ((kh * 64 + g * 16) ^ rdsw));
      #pragma unroll
      for (int ns = 0; ns < NF; ++ns)
        bfr[ns] = *(const bf16x8*)(lds + ABY + (wn * WCS + ns * 16 + r) * RB + ((kh * 64 + g * 16) ^ rdsw));
      #pragma unroll
      for (int ms = 0; ms < MF; ++ms)
        #pragma unroll
        for (int ns = 0; ns < NF; ++ns)
          acc[ms][ns] = __builtin_amdgcn_mfma_f32_16x16x32_bf16(af[ms], bfr[ns], acc[ms][ns], 0, 0, 0);
    }
  }

  // epilogue: C row = g*4+j, col = r (verified gfx950 16x16 C layout)
  #pragma unroll
  for (int ms = 0; ms < MF; ++ms) {
    int rowb = m0 + wm * WRS + ms * 16 + g * 4;
    #pragma unroll
    for (int ns = 0; ns < NF; ++ns) {
      int col = n0 + wn * WCS + ns * 16 + r;
      float bv = BIAS ? bias[col] : 0.f;
      f32x4 v = acc[ms][ns];
      #pragma unroll
      for (int j = 0; j < 4; ++j) {
        float o = v[j] + bv;
        if (RELU) o = fmaxf(o, 0.f);
        if constexpr (std::is_same<OT, float>::value)
          C[(long long)(rowb + j) * N + col] = o;
        else
          C[(long long)(rowb + j) * N + col] = __float2bfloat16(o);
      }
    }
  }
}

// ------------- batched transpose + cast: out[N,K](bf16) = in[K,N](f32) ---------
__global__ __launch_bounds__(256) void transpose_cast2(
    const float* __restrict__ inA, const float* __restrict__ inB, int zSplit,
    bf16* __restrict__ out, int K, int N)
{
  __shared__ unsigned short tile[32][33];
  int z = blockIdx.z;
  const float* ip = (z < zSplit) ? inA + (long long)z * K * N
                                 : inB + (long long)(z - zSplit) * K * N;
  unsigned short* op = (unsigned short*)out + (long long)z * K * N;
  int nx = blockIdx.x * 32, ky = blockIdx.y * 32;
  int tx = threadIdx.x, ty = threadIdx.y;   // (32,8)
  #pragma unroll
  for (int j = 0; j < 4; ++j)
    tile[ty + j * 8][tx] = f2us(ip[(long long)(ky + ty + j * 8) * N + nx + tx]);
  __syncthreads();
  #pragma unroll
  for (int j = 0; j < 4; ++j)
    op[(long long)(nx + ty + j * 8) * K + ky + tx] = tile[tx][ty + j * 8];
}

// ------------- embeddings (f32 tables) + sinusoidal PE -> bf16, both sides -----
__global__ __launch_bounds__(64) void embed2_k(
    const int* __restrict__ xids, const int* __restrict__ yids,
    const float* __restrict__ ex, const float* __restrict__ ey,
    bf16* __restrict__ ox, bf16* __restrict__ oy)
{
  int row = blockIdx.x;
  const int* ids; const float* emb; bf16* out; int S;
  if (row < BATCH * SXLEN) { ids = xids; emb = ex; out = ox; S = SXLEN; }
  else { row -= BATCH * SXLEN; ids = yids; emb = ey; out = oy; S = SYLEN; }
  int s = row % S;
  int lane = threadIdx.x;
  int id = ids[row];
  const float* e = emb + (long long)id * DMODEL;
  unsigned short* o = (unsigned short*)(out + (long long)row * DMODEL);
  #pragma unroll
  for (int j = 0; j < 8; ++j) {
    int d  = lane * 8 + j;
    int jj = d >> 1;
    float freq = __expf(-(float)(2 * jj) * (9.210340371976184f / 512.f)); // 10000^(-2j/512)
    float ang  = (float)s * freq;
    float pe   = (d & 1) ? cosf(ang) : sinf(ang);
    o[d] = f2us(e[d] + pe);
  }
}

// ---------------- attention core (one block per (b,h)) -------------------------
template<int CAUSAL>
__global__ __launch_bounds__(64) void attn_core(
    const bf16* __restrict__ Q, const bf16* __restrict__ Kk, const bf16* __restrict__ V,
    const int* __restrict__ tok, bf16* __restrict__ O, int Sq, int Sk)
{
  int bh = blockIdx.x; int b = bh >> 3; int h = bh & 7;
  __shared__ float Qs[SYLEN][DHEAD + 1], Ks[SYLEN][DHEAD + 1], Vs[SYLEN][DHEAD + 1];
  __shared__ float P[SYLEN][SYLEN + 1];
  __shared__ float msk[SYLEN];
  int t = threadIdx.x;

  for (int idx = t; idx < Sq * DHEAD; idx += 64) {
    int q = idx >> 6, d = idx & 63;
    Qs[q][d] = b2f(Q[((long long)(b * Sq + q)) * DMODEL + h * DHEAD + d]);
  }
  for (int idx = t; idx < Sk * DHEAD; idx += 64) {
    int k = idx >> 6, d = idx & 63;
    Ks[k][d] = b2f(Kk[((long long)(b * Sk + k)) * DMODEL + h * DHEAD + d]);
    Vs[k][d] = b2f(V [((long long)(b * Sk + k)) * DMODEL + h * DHEAD + d]);
  }
  if (t < Sk) msk[t] = (tok[b * Sk + t] != 0) ? 1.f : 0.f;
  __syncthreads();

  for (int idx = t; idx < Sq * Sk; idx += 64) {
    int q = idx / Sk, k = idx - q * Sk;
    float s = 0.f;
    #pragma unroll
    for (int i = 0; i < DHEAD; ++i) s += Qs[q][i] * Ks[k][i];
    s *= 0.125f;                       // 1/sqrt(64)
    bool m = (msk[k] != 0.f) && (!CAUSAL || k <= q);
    P[q][k] = m ? s : -1e9f;
  }
  __syncthreads();

  if (t < Sq) {
    float mx = -1e30f;
    for (int k = 0; k < Sk; ++k) mx = fmaxf(mx, P[t][k]);
    float sum = 0.f;
    for (int k = 0; k < Sk; ++k) { float e = __expf(P[t][k] - mx); P[t][k] = e; sum += e; }
    float inv = 1.f / sum;
    for (int k = 0; k < Sk; ++k) P[t][k] *= inv;
  }
  __syncthreads();

  int d = t;   // 64 lanes = 64 head dims
  for (int q = 0; q < Sq; ++q) {
    float o = 0.f;
    for (int k = 0; k < Sk; ++k) o += P[q][k] * Vs[k][d];
    O[((long long)(b * Sq + q)) * DMODEL + h * DHEAD + d] = __float2bfloat16(o);
  }
}

// ---- out = LN(R + P0 + P1 + bias) for split-K f32 partials, 1 wave/row --------
__global__ __launch_bounds__(64) void add_ln3_k(
    const bf16* __restrict__ R, const float* __restrict__ P, long long pStride,
    const float* __restrict__ bias,
    const float* __restrict__ gam, const float* __restrict__ bet,
    bf16* __restrict__ out)
{
  long long row = blockIdx.x;
  int lane = threadIdx.x;
  union { uint4 u; unsigned short s[8]; } ua, uo;
  ua.u = ((const uint4*)(R + row * DMODEL))[lane];
  const float4* p0 = (const float4*)(P + row * DMODEL);
  const float4* p1 = (const float4*)(P + pStride + row * DMODEL);
  float4 a0 = p0[lane * 2], a1 = p0[lane * 2 + 1];
  float4 c0 = p1[lane * 2], c1 = p1[lane * 2 + 1];
  float4 bi0 = ((const float4*)bias)[lane * 2], bi1 = ((const float4*)bias)[lane * 2 + 1];
  float pa[8] = {a0.x, a0.y, a0.z, a0.w, a1.x, a1.y, a1.z, a1.w};
  float pc[8] = {c0.x, c0.y, c0.z, c0.w, c1.x, c1.y, c1.z, c1.w};
  float pb[8] = {bi0.x, bi0.y, bi0.z, bi0.w, bi1.x, bi1.y, bi1.z, bi1.w};
  float x[8]; float s = 0.f, sq = 0.f;
  #pragma unroll
  for (int j = 0; j < 8; ++j) {
    x[j] = us2f(ua.s[j]) + pa[j] + pc[j] + pb[j];
    s += x[j]; sq += x[j] * x[j];
  }
  #pragma unroll
  for (int o = 32; o > 0; o >>= 1) { s += __shfl_xor(s, o); sq += __shfl_xor(sq, o); }
  float mean = s * (1.f / DMODEL);
  float var  = sq * (1.f / DMODEL) - mean * mean;
  float inv  = rsqrtf(var + 1e-5f);
  float4 g0 = ((const float4*)gam)[lane * 2], g1 = ((const float4*)gam)[lane * 2 + 1];
  float4 b0 = ((const float4*)bet)[lane * 2], b1 = ((const float4*)bet)[lane * 2 + 1];
  float gg[8] = {g0.x, g0.y, g0.z, g0.w, g1.x, g1.y, g1.z, g1.w};
  float bb[8] = {b0.x, b0.y, b0.z, b0.w, b1.x, b1.y, b1.z, b1.w};
  #pragma unroll
  for (int j = 0; j < 8; ++j)
    uo.s[j] = f2us(gg[j] * (x[j] - mean) * inv + bb[j]);
  ((uint4*)(out + row * DMODEL))[lane] = uo.u;
}

// ================================================================================
extern "C" void kernel_launch(void* const* d_in, const int* in_sizes, int n_in,
                              void* d_out, int out_size, void* d_ws, size_t ws_size,
                              hipStream_t stream)
{
  const int*   x        = (const int*)  d_in[0];
  const int*   y        = (const int*)  d_in[1];
  const float* emb_x    = (const float*)d_in[2];
  const float* emb_y    = (const float*)d_in[3];
  const float* enc_attn_w = (const float*)d_in[4];
  const float* enc_attn_b = (const float*)d_in[5];
  const float* enc_ln     = (const float*)d_in[6];
  const float* enc_f0w    = (const float*)d_in[7];
  const float* enc_f0b    = (const float*)d_in[8];
  const float* enc_f1w    = (const float*)d_in[9];
  const float* enc_f1b    = (const float*)d_in[10];
  const float* dec_attn_w = (const float*)d_in[11];
  const float* dec_attn_b = (const float*)d_in[12];
  const float* dec_ln     = (const float*)d_in[13];
  const float* dec_f0w    = (const float*)d_in[14];
  const float* dec_f0b    = (const float*)d_in[15];
  const float* dec_f1w    = (const float*)d_in[16];
  const float* dec_f1b    = (const float*)d_in[17];
  const float* fc_w       = (const float*)d_in[18];
  const float* fc_b       = (const float*)d_in[19];

  const int MX = BATCH * SXLEN;              // 3840
  const int MY = BATCH * SYLEN;              // 4352
  const long long DD = (long long)DMODEL * DMODEL;
  const long long SMEL = (long long)MY * DMODEL;
  const long long MXEL = (long long)MX * DMODEL;
  const long long FFEL = (long long)DMODEL * HFF;
  const long long PST  = (long long)MY * DMODEL;   // split-K partial stride

  // ---- workspace carve ----
  char* p = (char*)d_ws;
  auto alloc = [&](long long elems) -> bf16* {
    bf16* r = (bf16*)p; p += ((elems * 2 + 255) / 256) * 256; return r;
  };
  bf16* wt_attn = alloc(72 * DD);
  bf16* wt_f0   = alloc(12 * FFEL);
  bf16* wt_f1   = alloc(12 * FFEL);
  bf16* wt_fc   = alloc(32000LL * DMODEL);
  bf16* hx  = alloc(SMEL);
  bf16* hy  = alloc(SMEL);
  bf16* qb  = alloc(3 * SMEL);
  bf16* ao  = alloc(SMEL);
  bf16* h0  = alloc(SMEL);
  bf16* h1  = alloc(SMEL);
  bf16* mid = alloc((long long)MY * HFF);
  bf16* ckv = alloc(12 * MXEL);
  float* fp = (float*)alloc(2LL * MY * DMODEL * 2);  // 2 f32 split-K partials
  if ((size_t)(p - (char*)d_ws) > ws_size) return;

  bf16* wt_enc_attn = wt_attn;
  bf16* wt_dec_attn = wt_attn + 24 * DD;
  bf16* wt_enc_f0   = wt_f0;
  bf16* wt_dec_f0   = wt_f0 + 6 * FFEL;
  bf16* wt_enc_f1   = wt_f1;
  bf16* wt_dec_f1   = wt_f1 + 6 * FFEL;

  dim3 tb(32, 8);
  transpose_cast2<<<dim3(16, 16, 72), tb, 0, stream>>>(enc_attn_w, dec_attn_w, 24, wt_attn, DMODEL, DMODEL);
  transpose_cast2<<<dim3(64, 16, 12), tb, 0, stream>>>(enc_f0w, dec_f0w, 6, wt_f0, DMODEL, HFF);
  transpose_cast2<<<dim3(16, 64, 12), tb, 0, stream>>>(enc_f1w, dec_f1w, 6, wt_f1, HFF, DMODEL);
  transpose_cast2<<<dim3(1000, 16, 1), tb, 0, stream>>>(fc_w, fc_w, 1, wt_fc, DMODEL, 32000);

  embed2_k<<<MX + MY, 64, 0, stream>>>(x, y, emb_x, emb_y, hx, hy);

  // ---- encoder ----
  for (int i = 0; i < NLAYERS; ++i) {
    const bf16*  Wl = wt_enc_attn + (long long)i * 4 * DD;
    const float* Bl = enc_attn_b + (long long)i * 4 * DMODEL;
    const float* Lg = enc_ln + (size_t)i * 2048;
    gemm_t<0, 64, 128, 1, 2, 0, 1, bf16><<<dim3(4, 60, 3), 128, 0, stream>>>(hx, Wl, Bl, qb,
        MX, DMODEL, DMODEL, DMODEL, DD, DMODEL, SMEL);
    attn_core<0><<<BATCH * NHEADS, 64, 0, stream>>>(qb, qb + SMEL, qb + 2 * SMEL, x, ao, SXLEN, SXLEN);
    // O-proj as split-K=2 -> f32 partials, then LN with residual
    gemm_t<0, 64, 128, 1, 2, 2, 0, float><<<dim3(4, 60, 2), 128, 0, stream>>>(ao,
        Wl + 3 * DD, Bl + 3 * DMODEL, fp, MX, DMODEL, 256, DMODEL, 0, 0, PST);
    add_ln3_k<<<MX, 64, 0, stream>>>(hx, fp, PST, Bl + 3 * DMODEL, Lg, Lg + 512, h0);
    gemm_t<1, 128, 128, 2, 2, 0, 1, bf16><<<dim3(16, 30, 1), 256, 0, stream>>>(h0,
        wt_enc_f0 + (long long)i * FFEL, enc_f0b + (long long)i * HFF, mid,
        MX, HFF, DMODEL, DMODEL, 0, 0, 0);
    gemm_t<0, 64, 128, 1, 2, 2, 0, float><<<dim3(4, 60, 2), 128, 0, stream>>>(mid,
        wt_enc_f1 + (long long)i * FFEL, enc_f1b, fp,
        MX, DMODEL, 1024, HFF, 0, 0, PST);
    add_ln3_k<<<MX, 64, 0, stream>>>(h0, fp, PST,
        enc_f1b + (long long)i * DMODEL, Lg + 1024, Lg + 1536, hx);
  }

  // ---- all 6 decoder layers' cross K/V in one z=12 launch ----
  gemm_t<0, 64, 128, 1, 2, 1, 1, bf16><<<dim3(4, 60, 12), 128, 0, stream>>>(hx, wt_dec_attn,
      dec_attn_b, ckv, MX, DMODEL, DMODEL, DMODEL, DD, DMODEL, MXEL);

  // ---- decoder ----
  for (int i = 0; i < NLAYERS; ++i) {
    const bf16*  Wl = wt_dec_attn + (long long)i * 8 * DD;
    const float* Bl = dec_attn_b + (long long)i * 8 * DMODEL;
    const float* Lg = dec_ln + (size_t)i * 3072;
    // self-attention
    gemm_t<0, 64, 128, 1, 2, 0, 1, bf16><<<dim3(4, 68, 3), 128, 0, stream>>>(hy, Wl, Bl, qb,
        MY, DMODEL, DMODEL, DMODEL, DD, DMODEL, SMEL);
    attn_core<1><<<BATCH * NHEADS, 64, 0, stream>>>(qb, qb + SMEL, qb + 2 * SMEL, y, ao, SYLEN, SYLEN);
    gemm_t<0, 64, 128, 1, 2, 2, 0, float><<<dim3(4, 68, 2), 128, 0, stream>>>(ao,
        Wl + 3 * DD, Bl + 3 * DMODEL, fp, MY, DMODEL, 256, DMODEL, 0, 0, PST);
    add_ln3_k<<<MY, 64, 0, stream>>>(hy, fp, PST, Bl + 3 * DMODEL, Lg, Lg + 512, h0);
    // cross-attention: q from h0; k/v precomputed in ckv (keep 64x64: grid floor)
    gemm_t<0, 64, 64, 2, 1, 0, 1, bf16><<<dim3(8, 68, 1), 128, 0, stream>>>(h0, Wl + 4 * DD, Bl + 4 * DMODEL, qb,
        MY, DMODEL, DMODEL, DMODEL, 0, 0, 0);
    attn_core<0><<<BATCH * NHEADS, 64, 0, stream>>>(qb, ckv + (long long)(2 * i) * MXEL,
        ckv + (long long)(2 * i + 1) * MXEL, x, ao, SYLEN, SXLEN);
    gemm_t<0, 64, 128, 1, 2, 2, 0, float><<<dim3(4, 68, 2), 128, 0, stream>>>(ao,
        Wl + 7 * DD, Bl + 7 * DMODEL, fp, MY, DMODEL, 256, DMODEL, 0, 0, PST);
    add_ln3_k<<<MY, 64, 0, stream>>>(h0, fp, PST, Bl + 7 * DMODEL, Lg + 1024, Lg + 1536, h0);
    // FFN
    gemm_t<1, 128, 128, 2, 2, 0, 1, bf16><<<dim3(16, 34, 1), 256, 0, stream>>>(h0,
        wt_dec_f0 + (long long)i * FFEL, dec_f0b + (long long)i * HFF, mid,
        MY, HFF, DMODEL, DMODEL, 0, 0, 0);
    gemm_t<0, 64, 128, 1, 2, 2, 0, float><<<dim3(4, 68, 2), 128, 0, stream>>>(mid,
        wt_dec_f1 + (long long)i * FFEL, dec_f1b, fp,
        MY, DMODEL, 1024, HFF, 0, 0, PST);
    add_ln3_k<<<MY, 64, 0, stream>>>(h0, fp, PST,
        dec_f1b + (long long)i * DMODEL, Lg + 2048, Lg + 2560, hy);
  }

  // ---- final vocab projection (f32 out, 256x256 tile, 8 waves) ----
  gemm_t<0, 256, 256, 4, 2, 0, 1, float><<<dim3(125, 17, 1), 512, 0, stream>>>(hy, wt_fc, fc_b,
      (float*)d_out, MY, 32000, DMODEL, DMODEL, 0, 0, 0);
}

// Round 13
// 1850.855 us; speedup vs baseline: 1.0664x; 1.0465x over previous
//
#include <hip/hip_runtime.h>
#include <hip/hip_bf16.h>
#include <stdint.h>
#include <type_traits>

typedef __hip_bfloat16 bf16;
typedef __attribute__((ext_vector_type(8))) short bf16x8;
typedef __attribute__((ext_vector_type(4))) float f32x4;

#define DMODEL 512
#define HFF    2048
#define NHEADS 8
#define NLAYERS 6
#define DHEAD  64
#define BATCH  256
#define SXLEN  15
#define SYLEN  17

__device__ __forceinline__ float us2f(unsigned short u) {
  union { unsigned int i; float f; } c; c.i = ((unsigned int)u) << 16; return c.f;
}
__device__ __forceinline__ unsigned short f2us(float f) {
  bf16 h = __float2bfloat16(f);
  return *reinterpret_cast<unsigned short*>(&h);
}
__device__ __forceinline__ float b2f(bf16 v) { return __bfloat162float(v); }

__device__ __forceinline__ void gload_lds16(const void* g, void* l) {
  __builtin_amdgcn_global_load_lds(
      (const __attribute__((address_space(1))) unsigned int*)g,
      (__attribute__((address_space(3))) unsigned int*)l, 16, 0, 0);
}

// ---------------- generic bf16 GEMM: C = A[M,ldk] @ Wt[N,ldk]^T (+bias, opt ReLU)
// Wt = transposed bf16 weight ([N,K] row-major, row stride ldk). bias f32.
// Tile MT x NT, wave grid WM x WN, BK=64, XOR-swizzled LDS (both sides).
// ZMAP=0: linear z strides. ZMAP=1: cross-KV map (z -> layer z/2, mat 5+z%2).
// ZMAP=2: split-K (z selects k-chunk of length K; C offset by cStride).
template<int RELU, int MT, int NT, int WM, int WN, int ZMAP, int BIAS, typename OT>
__global__ __launch_bounds__(WM * WN * 64) void gemm_t(
    const bf16* __restrict__ A, const bf16* __restrict__ Wt,
    const float* __restrict__ bias, OT* __restrict__ C,
    int M, int N, int K, int ldk,
    long long wStride, long long bStride, long long cStride)
{
  constexpr int BK  = 64;
  constexpr int TH  = WM * WN * 64;
  constexpr int RB  = BK * 2;         // 128B LDS rows
  constexpr int MF  = MT / WM / 16;
  constexpr int NF  = NT / WN / 16;
  constexpr int WRS = MT / WM;
  constexpr int WCS = NT / WN;
  constexpr int ABY = MT * RB;
  constexpr int BBY = NT * RB;

  const int z = blockIdx.z;
  long long koff = 0;
  if (ZMAP == 1) {
    int idx = (z >> 1) * 8 + 5 + (z & 1);
    Wt   += (long long)idx * wStride;
    bias += (long long)idx * bStride;
  } else if (ZMAP == 2) {
    koff = (long long)z * K;
  } else {
    Wt   += (long long)z * wStride;
    bias += (long long)z * bStride;
  }
  C += (long long)z * cStride;

  __shared__ __align__(16) char lds[ABY + BBY];
  const int t    = threadIdx.x;
  const int m0   = blockIdx.y * MT, n0 = blockIdx.x * NT;
  const int wid  = t >> 6, lane = t & 63;
  const int wm   = wid / WN, wn = wid % WN;
  const int g    = lane >> 4, r = lane & 15;

  f32x4 acc[MF][NF];
  #pragma unroll
  for (int i = 0; i < MF; ++i)
    #pragma unroll
    for (int j = 0; j < NF; ++j) acc[i][j] = (f32x4)0.f;

  const char* Ab = (const char*)(A  + (long long)m0 * ldk + koff);
  const char* Bb = (const char*)(Wt + (long long)n0 * ldk + koff);
  const int rowBytes = ldk * 2;
  const int rdsw = (r & 7) << 4;      // read-side swizzle

  for (int kt = 0; kt < K; kt += BK) {
    __syncthreads();
    #pragma unroll
    for (int off = 0; off < ABY; off += TH * 16) {
      int o = off + t * 16;
      int row = o >> 7, cb = (o & 127) ^ ((row & 7) << 4);   // pre-swizzled source
      gload_lds16(Ab + (long long)row * rowBytes + kt * 2 + cb, lds + o);
    }
    #pragma unroll
    for (int off = 0; off < BBY; off += TH * 16) {
      int o = off + t * 16;
      int row = o >> 7, cb = (o & 127) ^ ((row & 7) << 4);
      gload_lds16(Bb + (long long)row * rowBytes + kt * 2 + cb, lds + ABY + o);
    }
    __syncthreads();

    #pragma unroll
    for (int kh = 0; kh < BK / 32; ++kh) {
      bf16x8 af[MF], bfr[NF];
      #pragma unroll
      for (int ms = 0; ms < MF; ++ms)
        af[ms] = *(const bf16x8*)(lds + (wm * WRS + ms * 16 + r) * RB + ((kh * 64 + g * 16) ^ rdsw));
      #pragma unroll
      for (int ns = 0; ns < NF; ++ns)
        bfr[ns] = *(const bf16x8*)(lds + ABY + (wn * WCS + ns * 16 + r) * RB + ((kh * 64 + g * 16) ^ rdsw));
      #pragma unroll
      for (int ms = 0; ms < MF; ++ms)
        #pragma unroll
        for (int ns = 0; ns < NF; ++ns)
          acc[ms][ns] = __builtin_amdgcn_mfma_f32_16x16x32_bf16(af[ms], bfr[ns], acc[ms][ns], 0, 0, 0);
    }
  }

  // epilogue: C row = g*4+j, col = r (verified gfx950 16x16 C layout)
  #pragma unroll
  for (int ms = 0; ms < MF; ++ms) {
    int rowb = m0 + wm * WRS + ms * 16 + g * 4;
    #pragma unroll
    for (int ns = 0; ns < NF; ++ns) {
      int col = n0 + wn * WCS + ns * 16 + r;
      float bv = BIAS ? bias[col] : 0.f;
      f32x4 v = acc[ms][ns];
      #pragma unroll
      for (int j = 0; j < 4; ++j) {
        float o = v[j] + bv;
        if (RELU) o = fmaxf(o, 0.f);
        if constexpr (std::is_same<OT, float>::value)
          C[(long long)(rowb + j) * N + col] = o;
        else
          C[(long long)(rowb + j) * N + col] = __float2bfloat16(o);
      }
    }
  }
}

// ------------- batched transpose + cast: out[N,K](bf16) = in[K,N](f32) ---------
__global__ __launch_bounds__(256) void transpose_cast2(
    const float* __restrict__ inA, const float* __restrict__ inB, int zSplit,
    bf16* __restrict__ out, int K, int N)
{
  __shared__ unsigned short tile[32][33];
  int z = blockIdx.z;
  const float* ip = (z < zSplit) ? inA + (long long)z * K * N
                                 : inB + (long long)(z - zSplit) * K * N;
  unsigned short* op = (unsigned short*)out + (long long)z * K * N;
  int nx = blockIdx.x * 32, ky = blockIdx.y * 32;
  int tx = threadIdx.x, ty = threadIdx.y;   // (32,8)
  #pragma unroll
  for (int j = 0; j < 4; ++j)
    tile[ty + j * 8][tx] = f2us(ip[(long long)(ky + ty + j * 8) * N + nx + tx]);
  __syncthreads();
  #pragma unroll
  for (int j = 0; j < 4; ++j)
    op[(long long)(nx + ty + j * 8) * K + ky + tx] = tile[tx][ty + j * 8];
}

// ------------- embeddings (f32 tables) + sinusoidal PE -> bf16, both sides -----
__global__ __launch_bounds__(64) void embed2_k(
    const int* __restrict__ xids, const int* __restrict__ yids,
    const float* __restrict__ ex, const float* __restrict__ ey,
    bf16* __restrict__ ox, bf16* __restrict__ oy)
{
  int row = blockIdx.x;
  const int* ids; const float* emb; bf16* out; int S;
  if (row < BATCH * SXLEN) { ids = xids; emb = ex; out = ox; S = SXLEN; }
  else { row -= BATCH * SXLEN; ids = yids; emb = ey; out = oy; S = SYLEN; }
  int s = row % S;
  int lane = threadIdx.x;
  int id = ids[row];
  const float* e = emb + (long long)id * DMODEL;
  unsigned short* o = (unsigned short*)(out + (long long)row * DMODEL);
  #pragma unroll
  for (int j = 0; j < 8; ++j) {
    int d  = lane * 8 + j;
    int jj = d >> 1;
    float freq = __expf(-(float)(2 * jj) * (9.210340371976184f / 512.f)); // 10000^(-2j/512)
    float ang  = (float)s * freq;
    float pe   = (d & 1) ? cosf(ang) : sinf(ang);
    o[d] = f2us(e[d] + pe);
  }
}

// ---------------- attention core (one block per (b,h)) -------------------------
template<int CAUSAL>
__global__ __launch_bounds__(64) void attn_core(
    const bf16* __restrict__ Q, const bf16* __restrict__ Kk, const bf16* __restrict__ V,
    const int* __restrict__ tok, bf16* __restrict__ O, int Sq, int Sk)
{
  int bh = blockIdx.x; int b = bh >> 3; int h = bh & 7;
  __shared__ float Qs[SYLEN][DHEAD + 1], Ks[SYLEN][DHEAD + 1], Vs[SYLEN][DHEAD + 1];
  __shared__ float P[SYLEN][SYLEN + 1];
  __shared__ float msk[SYLEN];
  int t = threadIdx.x;

  for (int idx = t; idx < Sq * DHEAD; idx += 64) {
    int q = idx >> 6, d = idx & 63;
    Qs[q][d] = b2f(Q[((long long)(b * Sq + q)) * DMODEL + h * DHEAD + d]);
  }
  for (int idx = t; idx < Sk * DHEAD; idx += 64) {
    int k = idx >> 6, d = idx & 63;
    Ks[k][d] = b2f(Kk[((long long)(b * Sk + k)) * DMODEL + h * DHEAD + d]);
    Vs[k][d] = b2f(V [((long long)(b * Sk + k)) * DMODEL + h * DHEAD + d]);
  }
  if (t < Sk) msk[t] = (tok[b * Sk + t] != 0) ? 1.f : 0.f;
  __syncthreads();

  for (int idx = t; idx < Sq * Sk; idx += 64) {
    int q = idx / Sk, k = idx - q * Sk;
    float s = 0.f;
    #pragma unroll
    for (int i = 0; i < DHEAD; ++i) s += Qs[q][i] * Ks[k][i];
    s *= 0.125f;                       // 1/sqrt(64)
    bool m = (msk[k] != 0.f) && (!CAUSAL || k <= q);
    P[q][k] = m ? s : -1e9f;
  }
  __syncthreads();

  if (t < Sq) {
    float mx = -1e30f;
    for (int k = 0; k < Sk; ++k) mx = fmaxf(mx, P[t][k]);
    float sum = 0.f;
    for (int k = 0; k < Sk; ++k) { float e = __expf(P[t][k] - mx); P[t][k] = e; sum += e; }
    float inv = 1.f / sum;
    for (int k = 0; k < Sk; ++k) P[t][k] *= inv;
  }
  __syncthreads();

  int d = t;   // 64 lanes = 64 head dims
  for (int q = 0; q < Sq; ++q) {
    float o = 0.f;
    for (int k = 0; k < Sk; ++k) o += P[q][k] * Vs[k][d];
    O[((long long)(b * Sq + q)) * DMODEL + h * DHEAD + d] = __float2bfloat16(o);
  }
}

// ---- out = LN(R + P0 + P1 + bias) for split-K f32 partials, 1 wave/row --------
__global__ __launch_bounds__(64) void add_ln3_k(
    const bf16* __restrict__ R, const float* __restrict__ P, long long pStride,
    const float* __restrict__ bias,
    const float* __restrict__ gam, const float* __restrict__ bet,
    bf16* __restrict__ out)
{
  long long row = blockIdx.x;
  int lane = threadIdx.x;
  union { uint4 u; unsigned short s[8]; } ua, uo;
  ua.u = ((const uint4*)(R + row * DMODEL))[lane];
  const float4* p0 = (const float4*)(P + row * DMODEL);
  const float4* p1 = (const float4*)(P + pStride + row * DMODEL);
  float4 a0 = p0[lane * 2], a1 = p0[lane * 2 + 1];
  float4 c0 = p1[lane * 2], c1 = p1[lane * 2 + 1];
  float4 bi0 = ((const float4*)bias)[lane * 2], bi1 = ((const float4*)bias)[lane * 2 + 1];
  float pa[8] = {a0.x, a0.y, a0.z, a0.w, a1.x, a1.y, a1.z, a1.w};
  float pc[8] = {c0.x, c0.y, c0.z, c0.w, c1.x, c1.y, c1.z, c1.w};
  float pb[8] = {bi0.x, bi0.y, bi0.z, bi0.w, bi1.x, bi1.y, bi1.z, bi1.w};
  float x[8]; float s = 0.f, sq = 0.f;
  #pragma unroll
  for (int j = 0; j < 8; ++j) {
    x[j] = us2f(ua.s[j]) + pa[j] + pc[j] + pb[j];
    s += x[j]; sq += x[j] * x[j];
  }
  #pragma unroll
  for (int o = 32; o > 0; o >>= 1) { s += __shfl_xor(s, o); sq += __shfl_xor(sq, o); }
  float mean = s * (1.f / DMODEL);
  float var  = sq * (1.f / DMODEL) - mean * mean;
  float inv  = rsqrtf(var + 1e-5f);
  float4 g0 = ((const float4*)gam)[lane * 2], g1 = ((const float4*)gam)[lane * 2 + 1];
  float4 b0 = ((const float4*)bet)[lane * 2], b1 = ((const float4*)bet)[lane * 2 + 1];
  float gg[8] = {g0.x, g0.y, g0.z, g0.w, g1.x, g1.y, g1.z, g1.w};
  float bb[8] = {b0.x, b0.y, b0.z, b0.w, b1.x, b1.y, b1.z, b1.w};
  #pragma unroll
  for (int j = 0; j < 8; ++j)
    uo.s[j] = f2us(gg[j] * (x[j] - mean) * inv + bb[j]);
  ((uint4*)(out + row * DMODEL))[lane] = uo.u;
}

// ================================================================================
extern "C" void kernel_launch(void* const* d_in, const int* in_sizes, int n_in,
                              void* d_out, int out_size, void* d_ws, size_t ws_size,
                              hipStream_t stream)
{
  const int*   x        = (const int*)  d_in[0];
  const int*   y        = (const int*)  d_in[1];
  const float* emb_x    = (const float*)d_in[2];
  const float* emb_y    = (const float*)d_in[3];
  const float* enc_attn_w = (const float*)d_in[4];
  const float* enc_attn_b = (const float*)d_in[5];
  const float* enc_ln     = (const float*)d_in[6];
  const float* enc_f0w    = (const float*)d_in[7];
  const float* enc_f0b    = (const float*)d_in[8];
  const float* enc_f1w    = (const float*)d_in[9];
  const float* enc_f1b    = (const float*)d_in[10];
  const float* dec_attn_w = (const float*)d_in[11];
  const float* dec_attn_b = (const float*)d_in[12];
  const float* dec_ln     = (const float*)d_in[13];
  const float* dec_f0w    = (const float*)d_in[14];
  const float* dec_f0b    = (const float*)d_in[15];
  const float* dec_f1w    = (const float*)d_in[16];
  const float* dec_f1b    = (const float*)d_in[17];
  const float* fc_w       = (const float*)d_in[18];
  const float* fc_b       = (const float*)d_in[19];

  const int MX = BATCH * SXLEN;              // 3840
  const int MY = BATCH * SYLEN;              // 4352
  const long long DD = (long long)DMODEL * DMODEL;
  const long long SMEL = (long long)MY * DMODEL;
  const long long MXEL = (long long)MX * DMODEL;
  const long long FFEL = (long long)DMODEL * HFF;
  const long long PST  = (long long)MY * DMODEL;   // split-K partial stride

  // ---- workspace carve ----
  char* p = (char*)d_ws;
  auto alloc = [&](long long elems) -> bf16* {
    bf16* r = (bf16*)p; p += ((elems * 2 + 255) / 256) * 256; return r;
  };
  bf16* wt_attn = alloc(72 * DD);
  bf16* wt_f0   = alloc(12 * FFEL);
  bf16* wt_f1   = alloc(12 * FFEL);
  bf16* wt_fc   = alloc(32000LL * DMODEL);
  bf16* hx  = alloc(SMEL);
  bf16* hy  = alloc(SMEL);
  bf16* qb  = alloc(3 * SMEL);
  bf16* ao  = alloc(SMEL);
  bf16* h0  = alloc(SMEL);
  bf16* h1  = alloc(SMEL);
  bf16* mid = alloc((long long)MY * HFF);
  bf16* ckv = alloc(12 * MXEL);
  float* fp = (float*)alloc(2LL * MY * DMODEL * 2);  // 2 f32 split-K partials
  if ((size_t)(p - (char*)d_ws) > ws_size) return;

  bf16* wt_enc_attn = wt_attn;
  bf16* wt_dec_attn = wt_attn + 24 * DD;
  bf16* wt_enc_f0   = wt_f0;
  bf16* wt_dec_f0   = wt_f0 + 6 * FFEL;
  bf16* wt_enc_f1   = wt_f1;
  bf16* wt_dec_f1   = wt_f1 + 6 * FFEL;

  dim3 tb(32, 8);
  transpose_cast2<<<dim3(16, 16, 72), tb, 0, stream>>>(enc_attn_w, dec_attn_w, 24, wt_attn, DMODEL, DMODEL);
  transpose_cast2<<<dim3(64, 16, 12), tb, 0, stream>>>(enc_f0w, dec_f0w, 6, wt_f0, DMODEL, HFF);
  transpose_cast2<<<dim3(16, 64, 12), tb, 0, stream>>>(enc_f1w, dec_f1w, 6, wt_f1, HFF, DMODEL);
  transpose_cast2<<<dim3(1000, 16, 1), tb, 0, stream>>>(fc_w, fc_w, 1, wt_fc, DMODEL, 32000);

  embed2_k<<<MX + MY, 64, 0, stream>>>(x, y, emb_x, emb_y, hx, hy);

  // ---- encoder ----
  for (int i = 0; i < NLAYERS; ++i) {
    const bf16*  Wl = wt_enc_attn + (long long)i * 4 * DD;
    const float* Bl = enc_attn_b + (long long)i * 4 * DMODEL;
    const float* Lg = enc_ln + (size_t)i * 2048;
    gemm_t<0, 64, 64, 2, 2, 0, 1, bf16><<<dim3(8, 60, 3), 256, 0, stream>>>(hx, Wl, Bl, qb,
        MX, DMODEL, DMODEL, DMODEL, DD, DMODEL, SMEL);
    attn_core<0><<<BATCH * NHEADS, 64, 0, stream>>>(qb, qb + SMEL, qb + 2 * SMEL, x, ao, SXLEN, SXLEN);
    // O-proj as split-K=2 -> f32 partials, then LN with residual
    gemm_t<0, 64, 64, 2, 2, 2, 0, float><<<dim3(8, 60, 2), 256, 0, stream>>>(ao,
        Wl + 3 * DD, Bl + 3 * DMODEL, fp, MX, DMODEL, 256, DMODEL, 0, 0, PST);
    add_ln3_k<<<MX, 64, 0, stream>>>(hx, fp, PST, Bl + 3 * DMODEL, Lg, Lg + 512, h0);
    gemm_t<1, 128, 128, 2, 2, 0, 1, bf16><<<dim3(16, 30, 1), 256, 0, stream>>>(h0,
        wt_enc_f0 + (long long)i * FFEL, enc_f0b + (long long)i * HFF, mid,
        MX, HFF, DMODEL, DMODEL, 0, 0, 0);
    gemm_t<0, 64, 64, 2, 2, 2, 0, float><<<dim3(8, 60, 2), 256, 0, stream>>>(mid,
        wt_enc_f1 + (long long)i * FFEL, enc_f1b, fp,
        MX, DMODEL, 1024, HFF, 0, 0, PST);
    add_ln3_k<<<MX, 64, 0, stream>>>(h0, fp, PST,
        enc_f1b + (long long)i * DMODEL, Lg + 1024, Lg + 1536, hx);
  }

  // ---- all 6 decoder layers' cross K/V in one z=12 launch ----
  gemm_t<0, 64, 64, 2, 2, 1, 1, bf16><<<dim3(8, 60, 12), 256, 0, stream>>>(hx, wt_dec_attn,
      dec_attn_b, ckv, MX, DMODEL, DMODEL, DMODEL, DD, DMODEL, MXEL);

  // ---- decoder ----
  for (int i = 0; i < NLAYERS; ++i) {
    const bf16*  Wl = wt_dec_attn + (long long)i * 8 * DD;
    const float* Bl = dec_attn_b + (long long)i * 8 * DMODEL;
    const float* Lg = dec_ln + (size_t)i * 3072;
    // self-attention
    gemm_t<0, 64, 64, 2, 2, 0, 1, bf16><<<dim3(8, 68, 3), 256, 0, stream>>>(hy, Wl, Bl, qb,
        MY, DMODEL, DMODEL, DMODEL, DD, DMODEL, SMEL);
    attn_core<1><<<BATCH * NHEADS, 64, 0, stream>>>(qb, qb + SMEL, qb + 2 * SMEL, y, ao, SYLEN, SYLEN);
    gemm_t<0, 64, 64, 2, 2, 2, 0, float><<<dim3(8, 68, 2), 256, 0, stream>>>(ao,
        Wl + 3 * DD, Bl + 3 * DMODEL, fp, MY, DMODEL, 256, DMODEL, 0, 0, PST);
    add_ln3_k<<<MY, 64, 0, stream>>>(hy, fp, PST, Bl + 3 * DMODEL, Lg, Lg + 512, h0);
    // cross-attention: q from h0; k/v precomputed in ckv
    gemm_t<0, 64, 64, 2, 2, 0, 1, bf16><<<dim3(8, 68, 1), 256, 0, stream>>>(h0, Wl + 4 * DD, Bl + 4 * DMODEL, qb,
        MY, DMODEL, DMODEL, DMODEL, 0, 0, 0);
    attn_core<0><<<BATCH * NHEADS, 64, 0, stream>>>(qb, ckv + (long long)(2 * i) * MXEL,
        ckv + (long long)(2 * i + 1) * MXEL, x, ao, SYLEN, SXLEN);
    gemm_t<0, 64, 64, 2, 2, 2, 0, float><<<dim3(8, 68, 2), 256, 0, stream>>>(ao,
        Wl + 7 * DD, Bl + 7 * DMODEL, fp, MY, DMODEL, 256, DMODEL, 0, 0, PST);
    add_ln3_k<<<MY, 64, 0, stream>>>(h0, fp, PST, Bl + 7 * DMODEL, Lg + 1024, Lg + 1536, h0);
    // FFN
    gemm_t<1, 128, 128, 2, 2, 0, 1, bf16><<<dim3(16, 34, 1), 256, 0, stream>>>(h0,
        wt_dec_f0 + (long long)i * FFEL, dec_f0b + (long long)i * HFF, mid,
        MY, HFF, DMODEL, DMODEL, 0, 0, 0);
    gemm_t<0, 64, 64, 2, 2, 2, 0, float><<<dim3(8, 68, 2), 256, 0, stream>>>(mid,
        wt_dec_f1 + (long long)i * FFEL, dec_f1b, fp,
        MY, DMODEL, 1024, HFF, 0, 0, PST);
    add_ln3_k<<<MY, 64, 0, stream>>>(h0, fp, PST,
        dec_f1b + (long long)i * DMODEL, Lg + 2048, Lg + 2560, hy);
  }

  // ---- final vocab projection (f32 out, 256x256 tile, 8 waves) ----
  gemm_t<0, 256, 256, 4, 2, 0, 1, float><<<dim3(125, 17, 1), 512, 0, stream>>>(hy, wt_fc, fc_b,
      (float*)d_out, MY, 32000, DMODEL, DMODEL, 0, 0, 0);
}

// Round 14
// 1797.284 us; speedup vs baseline: 1.0982x; 1.0298x over previous
//
#include <hip/hip_runtime.h>
#include <hip/hip_bf16.h>
#include <stdint.h>
#include <type_traits>

typedef __hip_bfloat16 bf16;
typedef __attribute__((ext_vector_type(8))) short bf16x8;
typedef __attribute__((ext_vector_type(4))) float f32x4;

#define DMODEL 512
#define HFF    2048
#define NHEADS 8
#define NLAYERS 6
#define DHEAD  64
#define BATCH  256
#define SXLEN  15
#define SYLEN  17

__device__ __forceinline__ float us2f(unsigned short u) {
  union { unsigned int i; float f; } c; c.i = ((unsigned int)u) << 16; return c.f;
}
__device__ __forceinline__ unsigned short f2us(float f) {
  bf16 h = __float2bfloat16(f);
  return *reinterpret_cast<unsigned short*>(&h);
}
__device__ __forceinline__ float b2f(bf16 v) { return __bfloat162float(v); }

__device__ __forceinline__ void gload_lds16(const void* g, void* l) {
  __builtin_amdgcn_global_load_lds(
      (const __attribute__((address_space(1))) unsigned int*)g,
      (__attribute__((address_space(3))) unsigned int*)l, 16, 0, 0);
}

// ---------------- generic bf16 GEMM: C = A[M,ldk] @ Wt[N,ldk]^T (+bias, opt ReLU)
// Wt = transposed bf16 weight ([N,K] row-major, row stride ldk). bias f32.
// Tile MT x NT, wave grid WM x WN, BK=64, XOR-swizzled LDS (both sides).
// XSWZ=1: bijective XCD-aware block remap (m204) over the flattened (x,y) grid
// so each XCD owns a contiguous chunk of logical tiles (A-panel L2 locality).
// ZMAP=0: linear z strides. ZMAP=1: cross-KV map (z -> layer z/2, mat 5+z%2).
// ZMAP=2: split-K (z selects k-chunk of length K; C offset by cStride).
template<int RELU, int MT, int NT, int WM, int WN, int ZMAP, int BIAS, int XSWZ, typename OT>
__global__ __launch_bounds__(WM * WN * 64) void gemm_t(
    const bf16* __restrict__ A, const bf16* __restrict__ Wt,
    const float* __restrict__ bias, OT* __restrict__ C,
    int M, int N, int K, int ldk,
    long long wStride, long long bStride, long long cStride)
{
  constexpr int BK  = 64;
  constexpr int TH  = WM * WN * 64;
  constexpr int RB  = BK * 2;         // 128B LDS rows
  constexpr int MF  = MT / WM / 16;
  constexpr int NF  = NT / WN / 16;
  constexpr int WRS = MT / WM;
  constexpr int WCS = NT / WN;
  constexpr int ABY = MT * RB;
  constexpr int BBY = NT * RB;

  const int z = blockIdx.z;
  long long koff = 0;
  if (ZMAP == 1) {
    int idx = (z >> 1) * 8 + 5 + (z & 1);
    Wt   += (long long)idx * wStride;
    bias += (long long)idx * bStride;
  } else if (ZMAP == 2) {
    koff = (long long)z * K;
  } else {
    Wt   += (long long)z * wStride;
    bias += (long long)z * bStride;
  }
  C += (long long)z * cStride;

  // ---- block-id remap for XCD L2 locality (T1, bijective per m204) ----
  int bid = (int)blockIdx.y * (int)gridDim.x + (int)blockIdx.x;
  if (XSWZ) {
    const int nwg = (int)gridDim.x * (int)gridDim.y;
    const int q = nwg >> 3, r = nwg & 7;
    const int xcd = bid & 7, i = bid >> 3;
    bid = (xcd < r ? xcd * (q + 1) : r * (q + 1) + (xcd - r) * q) + i;
  }
  const int bx = bid % (int)gridDim.x;
  const int by = bid / (int)gridDim.x;

  __shared__ __align__(16) char lds[ABY + BBY];
  const int t    = threadIdx.x;
  const int m0   = by * MT, n0 = bx * NT;
  const int wid  = t >> 6, lane = t & 63;
  const int wm   = wid / WN, wn = wid % WN;
  const int g    = lane >> 4, r = lane & 15;

  f32x4 acc[MF][NF];
  #pragma unroll
  for (int i = 0; i < MF; ++i)
    #pragma unroll
    for (int j = 0; j < NF; ++j) acc[i][j] = (f32x4)0.f;

  const char* Ab = (const char*)(A  + (long long)m0 * ldk + koff);
  const char* Bb = (const char*)(Wt + (long long)n0 * ldk + koff);
  const int rowBytes = ldk * 2;
  const int rdsw = (r & 7) << 4;      // read-side swizzle

  for (int kt = 0; kt < K; kt += BK) {
    __syncthreads();
    #pragma unroll
    for (int off = 0; off < ABY; off += TH * 16) {
      int o = off + t * 16;
      int row = o >> 7, cb = (o & 127) ^ ((row & 7) << 4);   // pre-swizzled source
      gload_lds16(Ab + (long long)row * rowBytes + kt * 2 + cb, lds + o);
    }
    #pragma unroll
    for (int off = 0; off < BBY; off += TH * 16) {
      int o = off + t * 16;
      int row = o >> 7, cb = (o & 127) ^ ((row & 7) << 4);
      gload_lds16(Bb + (long long)row * rowBytes + kt * 2 + cb, lds + ABY + o);
    }
    __syncthreads();

    #pragma unroll
    for (int kh = 0; kh < BK / 32; ++kh) {
      bf16x8 af[MF], bfr[NF];
      #pragma unroll
      for (int ms = 0; ms < MF; ++ms)
        af[ms] = *(const bf16x8*)(lds + (wm * WRS + ms * 16 + r) * RB + ((kh * 64 + g * 16) ^ rdsw));
      #pragma unroll
      for (int ns = 0; ns < NF; ++ns)
        bfr[ns] = *(const bf16x8*)(lds + ABY + (wn * WCS + ns * 16 + r) * RB + ((kh * 64 + g * 16) ^ rdsw));
      #pragma unroll
      for (int ms = 0; ms < MF; ++ms)
        #pragma unroll
        for (int ns = 0; ns < NF; ++ns)
          acc[ms][ns] = __builtin_amdgcn_mfma_f32_16x16x32_bf16(af[ms], bfr[ns], acc[ms][ns], 0, 0, 0);
    }
  }

  // epilogue: C row = g*4+j, col = r (verified gfx950 16x16 C layout)
  #pragma unroll
  for (int ms = 0; ms < MF; ++ms) {
    int rowb = m0 + wm * WRS + ms * 16 + g * 4;
    #pragma unroll
    for (int ns = 0; ns < NF; ++ns) {
      int col = n0 + wn * WCS + ns * 16 + r;
      float bv = BIAS ? bias[col] : 0.f;
      f32x4 v = acc[ms][ns];
      #pragma unroll
      for (int j = 0; j < 4; ++j) {
        float o = v[j] + bv;
        if (RELU) o = fmaxf(o, 0.f);
        if constexpr (std::is_same<OT, float>::value)
          C[(long long)(rowb + j) * N + col] = o;
        else
          C[(long long)(rowb + j) * N + col] = __float2bfloat16(o);
      }
    }
  }
}

// ------------- batched transpose + cast: out[N,K](bf16) = in[K,N](f32) ---------
__global__ __launch_bounds__(256) void transpose_cast2(
    const float* __restrict__ inA, const float* __restrict__ inB, int zSplit,
    bf16* __restrict__ out, int K, int N)
{
  __shared__ unsigned short tile[32][33];
  int z = blockIdx.z;
  const float* ip = (z < zSplit) ? inA + (long long)z * K * N
                                 : inB + (long long)(z - zSplit) * K * N;
  unsigned short* op = (unsigned short*)out + (long long)z * K * N;
  int nx = blockIdx.x * 32, ky = blockIdx.y * 32;
  int tx = threadIdx.x, ty = threadIdx.y;   // (32,8)
  #pragma unroll
  for (int j = 0; j < 4; ++j)
    tile[ty + j * 8][tx] = f2us(ip[(long long)(ky + ty + j * 8) * N + nx + tx]);
  __syncthreads();
  #pragma unroll
  for (int j = 0; j < 4; ++j)
    op[(long long)(nx + ty + j * 8) * K + ky + tx] = tile[tx][ty + j * 8];
}

// ------------- embeddings (f32 tables) + sinusoidal PE -> bf16, both sides -----
__global__ __launch_bounds__(64) void embed2_k(
    const int* __restrict__ xids, const int* __restrict__ yids,
    const float* __restrict__ ex, const float* __restrict__ ey,
    bf16* __restrict__ ox, bf16* __restrict__ oy)
{
  int row = blockIdx.x;
  const int* ids; const float* emb; bf16* out; int S;
  if (row < BATCH * SXLEN) { ids = xids; emb = ex; out = ox; S = SXLEN; }
  else { row -= BATCH * SXLEN; ids = yids; emb = ey; out = oy; S = SYLEN; }
  int s = row % S;
  int lane = threadIdx.x;
  int id = ids[row];
  const float* e = emb + (long long)id * DMODEL;
  unsigned short* o = (unsigned short*)(out + (long long)row * DMODEL);
  #pragma unroll
  for (int j = 0; j < 8; ++j) {
    int d  = lane * 8 + j;
    int jj = d >> 1;
    float freq = __expf(-(float)(2 * jj) * (9.210340371976184f / 512.f)); // 10000^(-2j/512)
    float ang  = (float)s * freq;
    float pe   = (d & 1) ? cosf(ang) : sinf(ang);
    o[d] = f2us(e[d] + pe);
  }
}

// ---------------- attention core (one block per (b,h)) -------------------------
template<int CAUSAL>
__global__ __launch_bounds__(64) void attn_core(
    const bf16* __restrict__ Q, const bf16* __restrict__ Kk, const bf16* __restrict__ V,
    const int* __restrict__ tok, bf16* __restrict__ O, int Sq, int Sk)
{
  int bh = blockIdx.x; int b = bh >> 3; int h = bh & 7;
  __shared__ float Qs[SYLEN][DHEAD + 1], Ks[SYLEN][DHEAD + 1], Vs[SYLEN][DHEAD + 1];
  __shared__ float P[SYLEN][SYLEN + 1];
  __shared__ float msk[SYLEN];
  int t = threadIdx.x;

  for (int idx = t; idx < Sq * DHEAD; idx += 64) {
    int q = idx >> 6, d = idx & 63;
    Qs[q][d] = b2f(Q[((long long)(b * Sq + q)) * DMODEL + h * DHEAD + d]);
  }
  for (int idx = t; idx < Sk * DHEAD; idx += 64) {
    int k = idx >> 6, d = idx & 63;
    Ks[k][d] = b2f(Kk[((long long)(b * Sk + k)) * DMODEL + h * DHEAD + d]);
    Vs[k][d] = b2f(V [((long long)(b * Sk + k)) * DMODEL + h * DHEAD + d]);
  }
  if (t < Sk) msk[t] = (tok[b * Sk + t] != 0) ? 1.f : 0.f;
  __syncthreads();

  for (int idx = t; idx < Sq * Sk; idx += 64) {
    int q = idx / Sk, k = idx - q * Sk;
    float s = 0.f;
    #pragma unroll
    for (int i = 0; i < DHEAD; ++i) s += Qs[q][i] * Ks[k][i];
    s *= 0.125f;                       // 1/sqrt(64)
    bool m = (msk[k] != 0.f) && (!CAUSAL || k <= q);
    P[q][k] = m ? s : -1e9f;
  }
  __syncthreads();

  if (t < Sq) {
    float mx = -1e30f;
    for (int k = 0; k < Sk; ++k) mx = fmaxf(mx, P[t][k]);
    float sum = 0.f;
    for (int k = 0; k < Sk; ++k) { float e = __expf(P[t][k] - mx); P[t][k] = e; sum += e; }
    float inv = 1.f / sum;
    for (int k = 0; k < Sk; ++k) P[t][k] *= inv;
  }
  __syncthreads();

  int d = t;   // 64 lanes = 64 head dims
  for (int q = 0; q < Sq; ++q) {
    float o = 0.f;
    for (int k = 0; k < Sk; ++k) o += P[q][k] * Vs[k][d];
    O[((long long)(b * Sq + q)) * DMODEL + h * DHEAD + d] = __float2bfloat16(o);
  }
}

// ---- out = LN(R + P0 + P1 + bias) for split-K f32 partials, 1 wave/row --------
__global__ __launch_bounds__(64) void add_ln3_k(
    const bf16* __restrict__ R, const float* __restrict__ P, long long pStride,
    const float* __restrict__ bias,
    const float* __restrict__ gam, const float* __restrict__ bet,
    bf16* __restrict__ out)
{
  long long row = blockIdx.x;
  int lane = threadIdx.x;
  union { uint4 u; unsigned short s[8]; } ua, uo;
  ua.u = ((const uint4*)(R + row * DMODEL))[lane];
  const float4* p0 = (const float4*)(P + row * DMODEL);
  const float4* p1 = (const float4*)(P + pStride + row * DMODEL);
  float4 a0 = p0[lane * 2], a1 = p0[lane * 2 + 1];
  float4 c0 = p1[lane * 2], c1 = p1[lane * 2 + 1];
  float4 bi0 = ((const float4*)bias)[lane * 2], bi1 = ((const float4*)bias)[lane * 2 + 1];
  float pa[8] = {a0.x, a0.y, a0.z, a0.w, a1.x, a1.y, a1.z, a1.w};
  float pc[8] = {c0.x, c0.y, c0.z, c0.w, c1.x, c1.y, c1.z, c1.w};
  float pb[8] = {bi0.x, bi0.y, bi0.z, bi0.w, bi1.x, bi1.y, bi1.z, bi1.w};
  float x[8]; float s = 0.f, sq = 0.f;
  #pragma unroll
  for (int j = 0; j < 8; ++j) {
    x[j] = us2f(ua.s[j]) + pa[j] + pc[j] + pb[j];
    s += x[j]; sq += x[j] * x[j];
  }
  #pragma unroll
  for (int o = 32; o > 0; o >>= 1) { s += __shfl_xor(s, o); sq += __shfl_xor(sq, o); }
  float mean = s * (1.f / DMODEL);
  float var  = sq * (1.f / DMODEL) - mean * mean;
  float inv  = rsqrtf(var + 1e-5f);
  float4 g0 = ((const float4*)gam)[lane * 2], g1 = ((const float4*)gam)[lane * 2 + 1];
  float4 b0 = ((const float4*)bet)[lane * 2], b1 = ((const float4*)bet)[lane * 2 + 1];
  float gg[8] = {g0.x, g0.y, g0.z, g0.w, g1.x, g1.y, g1.z, g1.w};
  float bb[8] = {b0.x, b0.y, b0.z, b0.w, b1.x, b1.y, b1.z, b1.w};
  #pragma unroll
  for (int j = 0; j < 8; ++j)
    uo.s[j] = f2us(gg[j] * (x[j] - mean) * inv + bb[j]);
  ((uint4*)(out + row * DMODEL))[lane] = uo.u;
}

// ================================================================================
extern "C" void kernel_launch(void* const* d_in, const int* in_sizes, int n_in,
                              void* d_out, int out_size, void* d_ws, size_t ws_size,
                              hipStream_t stream)
{
  const int*   x        = (const int*)  d_in[0];
  const int*   y        = (const int*)  d_in[1];
  const float* emb_x    = (const float*)d_in[2];
  const float* emb_y    = (const float*)d_in[3];
  const float* enc_attn_w = (const float*)d_in[4];
  const float* enc_attn_b = (const float*)d_in[5];
  const float* enc_ln     = (const float*)d_in[6];
  const float* enc_f0w    = (const float*)d_in[7];
  const float* enc_f0b    = (const float*)d_in[8];
  const float* enc_f1w    = (const float*)d_in[9];
  const float* enc_f1b    = (const float*)d_in[10];
  const float* dec_attn_w = (const float*)d_in[11];
  const float* dec_attn_b = (const float*)d_in[12];
  const float* dec_ln     = (const float*)d_in[13];
  const float* dec_f0w    = (const float*)d_in[14];
  const float* dec_f0b    = (const float*)d_in[15];
  const float* dec_f1w    = (const float*)d_in[16];
  const float* dec_f1b    = (const float*)d_in[17];
  const float* fc_w       = (const float*)d_in[18];
  const float* fc_b       = (const float*)d_in[19];

  const int MX = BATCH * SXLEN;              // 3840
  const int MY = BATCH * SYLEN;              // 4352
  const long long DD = (long long)DMODEL * DMODEL;
  const long long SMEL = (long long)MY * DMODEL;
  const long long MXEL = (long long)MX * DMODEL;
  const long long FFEL = (long long)DMODEL * HFF;
  const long long PST  = (long long)MY * DMODEL;   // split-K partial stride

  // ---- workspace carve ----
  char* p = (char*)d_ws;
  auto alloc = [&](long long elems) -> bf16* {
    bf16* r = (bf16*)p; p += ((elems * 2 + 255) / 256) * 256; return r;
  };
  bf16* wt_attn = alloc(72 * DD);
  bf16* wt_f0   = alloc(12 * FFEL);
  bf16* wt_f1   = alloc(12 * FFEL);
  bf16* wt_fc   = alloc(32000LL * DMODEL);
  bf16* hx  = alloc(SMEL);
  bf16* hy  = alloc(SMEL);
  bf16* qb  = alloc(3 * SMEL);
  bf16* ao  = alloc(SMEL);
  bf16* h0  = alloc(SMEL);
  bf16* h1  = alloc(SMEL);
  bf16* mid = alloc((long long)MY * HFF);
  bf16* ckv = alloc(12 * MXEL);
  float* fp = (float*)alloc(2LL * MY * DMODEL * 2);  // 2 f32 split-K partials
  if ((size_t)(p - (char*)d_ws) > ws_size) return;

  bf16* wt_enc_attn = wt_attn;
  bf16* wt_dec_attn = wt_attn + 24 * DD;
  bf16* wt_enc_f0   = wt_f0;
  bf16* wt_dec_f0   = wt_f0 + 6 * FFEL;
  bf16* wt_enc_f1   = wt_f1;
  bf16* wt_dec_f1   = wt_f1 + 6 * FFEL;

  dim3 tb(32, 8);
  transpose_cast2<<<dim3(16, 16, 72), tb, 0, stream>>>(enc_attn_w, dec_attn_w, 24, wt_attn, DMODEL, DMODEL);
  transpose_cast2<<<dim3(64, 16, 12), tb, 0, stream>>>(enc_f0w, dec_f0w, 6, wt_f0, DMODEL, HFF);
  transpose_cast2<<<dim3(16, 64, 12), tb, 0, stream>>>(enc_f1w, dec_f1w, 6, wt_f1, HFF, DMODEL);
  transpose_cast2<<<dim3(1000, 16, 1), tb, 0, stream>>>(fc_w, fc_w, 1, wt_fc, DMODEL, 32000);

  embed2_k<<<MX + MY, 64, 0, stream>>>(x, y, emb_x, emb_y, hx, hy);

  // ---- encoder ----
  for (int i = 0; i < NLAYERS; ++i) {
    const bf16*  Wl = wt_enc_attn + (long long)i * 4 * DD;
    const float* Bl = enc_attn_b + (long long)i * 4 * DMODEL;
    const float* Lg = enc_ln + (size_t)i * 2048;
    gemm_t<0, 64, 64, 2, 2, 0, 1, 1, bf16><<<dim3(8, 60, 3), 256, 0, stream>>>(hx, Wl, Bl, qb,
        MX, DMODEL, DMODEL, DMODEL, DD, DMODEL, SMEL);
    attn_core<0><<<BATCH * NHEADS, 64, 0, stream>>>(qb, qb + SMEL, qb + 2 * SMEL, x, ao, SXLEN, SXLEN);
    // O-proj as split-K=2 -> f32 partials, then LN with residual
    gemm_t<0, 64, 64, 2, 2, 2, 0, 1, float><<<dim3(8, 60, 2), 256, 0, stream>>>(ao,
        Wl + 3 * DD, Bl + 3 * DMODEL, fp, MX, DMODEL, 256, DMODEL, 0, 0, PST);
    add_ln3_k<<<MX, 64, 0, stream>>>(hx, fp, PST, Bl + 3 * DMODEL, Lg, Lg + 512, h0);
    gemm_t<1, 128, 128, 2, 2, 0, 1, 1, bf16><<<dim3(16, 30, 1), 256, 0, stream>>>(h0,
        wt_enc_f0 + (long long)i * FFEL, enc_f0b + (long long)i * HFF, mid,
        MX, HFF, DMODEL, DMODEL, 0, 0, 0);
    gemm_t<0, 64, 64, 2, 2, 2, 0, 1, float><<<dim3(8, 60, 2), 256, 0, stream>>>(mid,
        wt_enc_f1 + (long long)i * FFEL, enc_f1b, fp,
        MX, DMODEL, 1024, HFF, 0, 0, PST);
    add_ln3_k<<<MX, 64, 0, stream>>>(h0, fp, PST,
        enc_f1b + (long long)i * DMODEL, Lg + 1024, Lg + 1536, hx);
  }

  // ---- all 6 decoder layers' cross K/V in one z=12 launch ----
  gemm_t<0, 64, 64, 2, 2, 1, 1, 1, bf16><<<dim3(8, 60, 12), 256, 0, stream>>>(hx, wt_dec_attn,
      dec_attn_b, ckv, MX, DMODEL, DMODEL, DMODEL, DD, DMODEL, MXEL);

  // ---- decoder ----
  for (int i = 0; i < NLAYERS; ++i) {
    const bf16*  Wl = wt_dec_attn + (long long)i * 8 * DD;
    const float* Bl = dec_attn_b + (long long)i * 8 * DMODEL;
    const float* Lg = dec_ln + (size_t)i * 3072;
    // self-attention
    gemm_t<0, 64, 64, 2, 2, 0, 1, 1, bf16><<<dim3(8, 68, 3), 256, 0, stream>>>(hy, Wl, Bl, qb,
        MY, DMODEL, DMODEL, DMODEL, DD, DMODEL, SMEL);
    attn_core<1><<<BATCH * NHEADS, 64, 0, stream>>>(qb, qb + SMEL, qb + 2 * SMEL, y, ao, SYLEN, SYLEN);
    gemm_t<0, 64, 64, 2, 2, 2, 0, 1, float><<<dim3(8, 68, 2), 256, 0, stream>>>(ao,
        Wl + 3 * DD, Bl + 3 * DMODEL, fp, MY, DMODEL, 256, DMODEL, 0, 0, PST);
    add_ln3_k<<<MY, 64, 0, stream>>>(hy, fp, PST, Bl + 3 * DMODEL, Lg, Lg + 512, h0);
    // cross-attention: q from h0; k/v precomputed in ckv
    gemm_t<0, 64, 64, 2, 2, 0, 1, 1, bf16><<<dim3(8, 68, 1), 256, 0, stream>>>(h0, Wl + 4 * DD, Bl + 4 * DMODEL, qb,
        MY, DMODEL, DMODEL, DMODEL, 0, 0, 0);
    attn_core<0><<<BATCH * NHEADS, 64, 0, stream>>>(qb, ckv + (long long)(2 * i) * MXEL,
        ckv + (long long)(2 * i + 1) * MXEL, x, ao, SYLEN, SXLEN);
    gemm_t<0, 64, 64, 2, 2, 2, 0, 1, float><<<dim3(8, 68, 2), 256, 0, stream>>>(ao,
        Wl + 7 * DD, Bl + 7 * DMODEL, fp, MY, DMODEL, 256, DMODEL, 0, 0, PST);
    add_ln3_k<<<MY, 64, 0, stream>>>(h0, fp, PST, Bl + 7 * DMODEL, Lg + 1024, Lg + 1536, h0);
    // FFN
    gemm_t<1, 128, 128, 2, 2, 0, 1, 1, bf16><<<dim3(16, 34, 1), 256, 0, stream>>>(h0,
        wt_dec_f0 + (long long)i * FFEL, dec_f0b + (long long)i * HFF, mid,
        MY, HFF, DMODEL, DMODEL, 0, 0, 0);
    gemm_t<0, 64, 64, 2, 2, 2, 0, 1, float><<<dim3(8, 68, 2), 256, 0, stream>>>(mid,
        wt_dec_f1 + (long long)i * FFEL, dec_f1b, fp,
        MY, DMODEL, 1024, HFF, 0, 0, PST);
    add_ln3_k<<<MY, 64, 0, stream>>>(h0, fp, PST,
        dec_f1b + (long long)i * DMODEL, Lg + 2048, Lg + 2560, hy);
  }

  // ---- final vocab projection (f32 out, 256x256 tile, 8 waves) ----
  gemm_t<0, 256, 256, 4, 2, 0, 1, 1, float><<<dim3(125, 17, 1), 512, 0, stream>>>(hy, wt_fc, fc_b,
      (float*)d_out, MY, 32000, DMODEL, DMODEL, 0, 0, 0);
}

// Round 16
// 1783.000 us; speedup vs baseline: 1.1070x; 1.0080x over previous
//
#include <hip/hip_runtime.h>
#include <hip/hip_bf16.h>
#include <stdint.h>
#include <type_traits>

typedef __hip_bfloat16 bf16;
typedef __attribute__((ext_vector_type(8))) short bf16x8;
typedef __attribute__((ext_vector_type(4))) float f32x4;

#define DMODEL 512
#define HFF    2048
#define NHEADS 8
#define NLAYERS 6
#define DHEAD  64
#define BATCH  256
#define SXLEN  15
#define SYLEN  17

__device__ __forceinline__ float us2f(unsigned short u) {
  union { unsigned int i; float f; } c; c.i = ((unsigned int)u) << 16; return c.f;
}
__device__ __forceinline__ unsigned short f2us(float f) {
  bf16 h = __float2bfloat16(f);
  return *reinterpret_cast<unsigned short*>(&h);
}
__device__ __forceinline__ float b2f(bf16 v) { return __bfloat162float(v); }

__device__ __forceinline__ void gload_lds16(const void* g, void* l) {
  __builtin_amdgcn_global_load_lds(
      (const __attribute__((address_space(1))) unsigned int*)g,
      (__attribute__((address_space(3))) unsigned int*)l, 16, 0, 0);
}

// ---------------- generic bf16 GEMM: C = A[M,ldk] @ Wt[N,ldk]^T (+bias, opt ReLU)
// Wt = transposed bf16 weight ([N,K] row-major, row stride ldk). bias f32.
// Tile MT x NT, wave grid WM x WN, BK=64, XOR-swizzled LDS (both sides).
// XSWZ=1: bijective XCD-aware block remap (m204) over the flattened (x,y) grid
// so each XCD owns a contiguous chunk of logical tiles (A-panel L2 locality).
// ZMAP=0: linear z strides. ZMAP=1: cross-KV map (z -> layer z/2, mat 5+z%2).
// ZMAP=2: split-K (z selects k-chunk of length K; C offset by cStride).
template<int RELU, int MT, int NT, int WM, int WN, int ZMAP, int BIAS, int XSWZ, typename OT>
__global__ __launch_bounds__(WM * WN * 64) void gemm_t(
    const bf16* __restrict__ A, const bf16* __restrict__ Wt,
    const float* __restrict__ bias, OT* __restrict__ C,
    int M, int N, int K, int ldk,
    long long wStride, long long bStride, long long cStride)
{
  constexpr int BK  = 64;
  constexpr int TH  = WM * WN * 64;
  constexpr int RB  = BK * 2;         // 128B LDS rows
  constexpr int MF  = MT / WM / 16;
  constexpr int NF  = NT / WN / 16;
  constexpr int WRS = MT / WM;
  constexpr int WCS = NT / WN;
  constexpr int ABY = MT * RB;
  constexpr int BBY = NT * RB;

  const int z = blockIdx.z;
  long long koff = 0;
  if (ZMAP == 1) {
    int idx = (z >> 1) * 8 + 5 + (z & 1);
    Wt   += (long long)idx * wStride;
    bias += (long long)idx * bStride;
  } else if (ZMAP == 2) {
    koff = (long long)z * K;
  } else {
    Wt   += (long long)z * wStride;
    bias += (long long)z * bStride;
  }
  C += (long long)z * cStride;

  // ---- block-id remap for XCD L2 locality (T1, bijective per m204) ----
  int bid = (int)blockIdx.y * (int)gridDim.x + (int)blockIdx.x;
  if (XSWZ) {
    const int nwg = (int)gridDim.x * (int)gridDim.y;
    const int q = nwg >> 3, r = nwg & 7;
    const int xcd = bid & 7, i = bid >> 3;
    bid = (xcd < r ? xcd * (q + 1) : r * (q + 1) + (xcd - r) * q) + i;
  }
  const int bx = bid % (int)gridDim.x;
  const int by = bid / (int)gridDim.x;

  __shared__ __align__(16) char lds[ABY + BBY];
  const int t    = threadIdx.x;
  const int m0   = by * MT, n0 = bx * NT;
  const int wid  = t >> 6, lane = t & 63;
  const int wm   = wid / WN, wn = wid % WN;
  const int g    = lane >> 4, r = lane & 15;

  f32x4 acc[MF][NF];
  #pragma unroll
  for (int i = 0; i < MF; ++i)
    #pragma unroll
    for (int j = 0; j < NF; ++j) acc[i][j] = (f32x4)0.f;

  const char* Ab = (const char*)(A  + (long long)m0 * ldk + koff);
  const char* Bb = (const char*)(Wt + (long long)n0 * ldk + koff);
  const int rowBytes = ldk * 2;
  const int rdsw = (r & 7) << 4;      // read-side swizzle

  for (int kt = 0; kt < K; kt += BK) {
    __syncthreads();
    #pragma unroll
    for (int off = 0; off < ABY; off += TH * 16) {
      int o = off + t * 16;
      int row = o >> 7, cb = (o & 127) ^ ((row & 7) << 4);   // pre-swizzled source
      gload_lds16(Ab + (long long)row * rowBytes + kt * 2 + cb, lds + o);
    }
    #pragma unroll
    for (int off = 0; off < BBY; off += TH * 16) {
      int o = off + t * 16;
      int row = o >> 7, cb = (o & 127) ^ ((row & 7) << 4);
      gload_lds16(Bb + (long long)row * rowBytes + kt * 2 + cb, lds + ABY + o);
    }
    __syncthreads();

    #pragma unroll
    for (int kh = 0; kh < BK / 32; ++kh) {
      bf16x8 af[MF], bfr[NF];
      #pragma unroll
      for (int ms = 0; ms < MF; ++ms)
        af[ms] = *(const bf16x8*)(lds + (wm * WRS + ms * 16 + r) * RB + ((kh * 64 + g * 16) ^ rdsw));
      #pragma unroll
      for (int ns = 0; ns < NF; ++ns)
        bfr[ns] = *(const bf16x8*)(lds + ABY + (wn * WCS + ns * 16 + r) * RB + ((kh * 64 + g * 16) ^ rdsw));
      #pragma unroll
      for (int ms = 0; ms < MF; ++ms)
        #pragma unroll
        for (int ns = 0; ns < NF; ++ns)
          acc[ms][ns] = __builtin_amdgcn_mfma_f32_16x16x32_bf16(af[ms], bfr[ns], acc[ms][ns], 0, 0, 0);
    }
  }

  // epilogue: C row = g*4+j, col = r (verified gfx950 16x16 C layout)
  #pragma unroll
  for (int ms = 0; ms < MF; ++ms) {
    int rowb = m0 + wm * WRS + ms * 16 + g * 4;
    #pragma unroll
    for (int ns = 0; ns < NF; ++ns) {
      int col = n0 + wn * WCS + ns * 16 + r;
      float bv = BIAS ? bias[col] : 0.f;
      f32x4 v = acc[ms][ns];
      #pragma unroll
      for (int j = 0; j < 4; ++j) {
        float o = v[j] + bv;
        if (RELU) o = fmaxf(o, 0.f);
        if constexpr (std::is_same<OT, float>::value)
          C[(long long)(rowb + j) * N + col] = o;
        else
          C[(long long)(rowb + j) * N + col] = __float2bfloat16(o);
      }
    }
  }
}

// ------------- batched transpose + cast: out[N,K](bf16) = in[K,N](f32) ---------
__global__ __launch_bounds__(256) void transpose_cast2(
    const float* __restrict__ inA, const float* __restrict__ inB, int zSplit,
    bf16* __restrict__ out, int K, int N)
{
  __shared__ unsigned short tile[32][33];
  int z = blockIdx.z;
  const float* ip = (z < zSplit) ? inA + (long long)z * K * N
                                 : inB + (long long)(z - zSplit) * K * N;
  unsigned short* op = (unsigned short*)out + (long long)z * K * N;
  int nx = blockIdx.x * 32, ky = blockIdx.y * 32;
  int tx = threadIdx.x, ty = threadIdx.y;   // (32,8)
  #pragma unroll
  for (int j = 0; j < 4; ++j)
    tile[ty + j * 8][tx] = f2us(ip[(long long)(ky + ty + j * 8) * N + nx + tx]);
  __syncthreads();
  #pragma unroll
  for (int j = 0; j < 4; ++j)
    op[(long long)(nx + ty + j * 8) * K + ky + tx] = tile[tx][ty + j * 8];
}

// ------------- embeddings (f32 tables) + sinusoidal PE -> bf16, both sides -----
__global__ __launch_bounds__(64) void embed2_k(
    const int* __restrict__ xids, const int* __restrict__ yids,
    const float* __restrict__ ex, const float* __restrict__ ey,
    bf16* __restrict__ ox, bf16* __restrict__ oy)
{
  int row = blockIdx.x;
  const int* ids; const float* emb; bf16* out; int S;
  if (row < BATCH * SXLEN) { ids = xids; emb = ex; out = ox; S = SXLEN; }
  else { row -= BATCH * SXLEN; ids = yids; emb = ey; out = oy; S = SYLEN; }
  int s = row % S;
  int lane = threadIdx.x;
  int id = ids[row];
  const float* e = emb + (long long)id * DMODEL;
  unsigned short* o = (unsigned short*)(out + (long long)row * DMODEL);
  #pragma unroll
  for (int j = 0; j < 8; ++j) {
    int d  = lane * 8 + j;
    int jj = d >> 1;
    float freq = __expf(-(float)(2 * jj) * (9.210340371976184f / 512.f)); // 10000^(-2j/512)
    float ang  = (float)s * freq;
    float pe   = (d & 1) ? cosf(ang) : sinf(ang);
    o[d] = f2us(e[d] + pe);
  }
}

// ---------------- attention core (one block per (b,h)) -------------------------
template<int CAUSAL>
__global__ __launch_bounds__(64) void attn_core(
    const bf16* __restrict__ Q, const bf16* __restrict__ Kk, const bf16* __restrict__ V,
    const int* __restrict__ tok, bf16* __restrict__ O, int Sq, int Sk)
{
  int bh = blockIdx.x; int b = bh >> 3; int h = bh & 7;
  __shared__ float Qs[SYLEN][DHEAD + 1], Ks[SYLEN][DHEAD + 1], Vs[SYLEN][DHEAD + 1];
  __shared__ float P[SYLEN][SYLEN + 1];
  __shared__ float msk[SYLEN];
  int t = threadIdx.x;

  for (int idx = t; idx < Sq * DHEAD; idx += 64) {
    int q = idx >> 6, d = idx & 63;
    Qs[q][d] = b2f(Q[((long long)(b * Sq + q)) * DMODEL + h * DHEAD + d]);
  }
  for (int idx = t; idx < Sk * DHEAD; idx += 64) {
    int k = idx >> 6, d = idx & 63;
    Ks[k][d] = b2f(Kk[((long long)(b * Sk + k)) * DMODEL + h * DHEAD + d]);
    Vs[k][d] = b2f(V [((long long)(b * Sk + k)) * DMODEL + h * DHEAD + d]);
  }
  if (t < Sk) msk[t] = (tok[b * Sk + t] != 0) ? 1.f : 0.f;
  __syncthreads();

  for (int idx = t; idx < Sq * Sk; idx += 64) {
    int q = idx / Sk, k = idx - q * Sk;
    float s = 0.f;
    #pragma unroll
    for (int i = 0; i < DHEAD; ++i) s += Qs[q][i] * Ks[k][i];
    s *= 0.125f;                       // 1/sqrt(64)
    bool m = (msk[k] != 0.f) && (!CAUSAL || k <= q);
    P[q][k] = m ? s : -1e9f;
  }
  __syncthreads();

  if (t < Sq) {
    float mx = -1e30f;
    for (int k = 0; k < Sk; ++k) mx = fmaxf(mx, P[t][k]);
    float sum = 0.f;
    for (int k = 0; k < Sk; ++k) { float e = __expf(P[t][k] - mx); P[t][k] = e; sum += e; }
    float inv = 1.f / sum;
    for (int k = 0; k < Sk; ++k) P[t][k] *= inv;
  }
  __syncthreads();

  int d = t;   // 64 lanes = 64 head dims
  for (int q = 0; q < Sq; ++q) {
    float o = 0.f;
    for (int k = 0; k < Sk; ++k) o += P[q][k] * Vs[k][d];
    O[((long long)(b * Sq + q)) * DMODEL + h * DHEAD + d] = __float2bfloat16(o);
  }
}

// ---- out = LN(R + P0 + P1 + bias) for split-K f32 partials, 1 wave/row --------
__global__ __launch_bounds__(64) void add_ln3_k(
    const bf16* __restrict__ R, const float* __restrict__ P, long long pStride,
    const float* __restrict__ bias,
    const float* __restrict__ gam, const float* __restrict__ bet,
    bf16* __restrict__ out)
{
  long long row = blockIdx.x;
  int lane = threadIdx.x;
  union { uint4 u; unsigned short s[8]; } ua, uo;
  ua.u = ((const uint4*)(R + row * DMODEL))[lane];
  const float4* p0 = (const float4*)(P + row * DMODEL);
  const float4* p1 = (const float4*)(P + pStride + row * DMODEL);
  float4 a0 = p0[lane * 2], a1 = p0[lane * 2 + 1];
  float4 c0 = p1[lane * 2], c1 = p1[lane * 2 + 1];
  float4 bi0 = ((const float4*)bias)[lane * 2], bi1 = ((const float4*)bias)[lane * 2 + 1];
  float pa[8] = {a0.x, a0.y, a0.z, a0.w, a1.x, a1.y, a1.z, a1.w};
  float pc[8] = {c0.x, c0.y, c0.z, c0.w, c1.x, c1.y, c1.z, c1.w};
  float pb[8] = {bi0.x, bi0.y, bi0.z, bi0.w, bi1.x, bi1.y, bi1.z, bi1.w};
  float x[8]; float s = 0.f, sq = 0.f;
  #pragma unroll
  for (int j = 0; j < 8; ++j) {
    x[j] = us2f(ua.s[j]) + pa[j] + pc[j] + pb[j];
    s += x[j]; sq += x[j] * x[j];
  }
  #pragma unroll
  for (int o = 32; o > 0; o >>= 1) { s += __shfl_xor(s, o); sq += __shfl_xor(sq, o); }
  float mean = s * (1.f / DMODEL);
  float var  = sq * (1.f / DMODEL) - mean * mean;
  float inv  = rsqrtf(var + 1e-5f);
  float4 g0 = ((const float4*)gam)[lane * 2], g1 = ((const float4*)gam)[lane * 2 + 1];
  float4 b0 = ((const float4*)bet)[lane * 2], b1 = ((const float4*)bet)[lane * 2 + 1];
  float gg[8] = {g0.x, g0.y, g0.z, g0.w, g1.x, g1.y, g1.z, g1.w};
  float bb[8] = {b0.x, b0.y, b0.z, b0.w, b1.x, b1.y, b1.z, b1.w};
  #pragma unroll
  for (int j = 0; j < 8; ++j)
    uo.s[j] = f2us(gg[j] * (x[j] - mean) * inv + bb[j]);
  ((uint4*)(out + row * DMODEL))[lane] = uo.u;
}

// ================================================================================
extern "C" void kernel_launch(void* const* d_in, const int* in_sizes, int n_in,
                              void* d_out, int out_size, void* d_ws, size_t ws_size,
                              hipStream_t stream)
{
  const int*   x        = (const int*)  d_in[0];
  const int*   y        = (const int*)  d_in[1];
  const float* emb_x    = (const float*)d_in[2];
  const float* emb_y    = (const float*)d_in[3];
  const float* enc_attn_w = (const float*)d_in[4];
  const float* enc_attn_b = (const float*)d_in[5];
  const float* enc_ln     = (const float*)d_in[6];
  const float* enc_f0w    = (const float*)d_in[7];
  const float* enc_f0b    = (const float*)d_in[8];
  const float* enc_f1w    = (const float*)d_in[9];
  const float* enc_f1b    = (const float*)d_in[10];
  const float* dec_attn_w = (const float*)d_in[11];
  const float* dec_attn_b = (const float*)d_in[12];
  const float* dec_ln     = (const float*)d_in[13];
  const float* dec_f0w    = (const float*)d_in[14];
  const float* dec_f0b    = (const float*)d_in[15];
  const float* dec_f1w    = (const float*)d_in[16];
  const float* dec_f1b    = (const float*)d_in[17];
  const float* fc_w       = (const float*)d_in[18];
  const float* fc_b       = (const float*)d_in[19];

  const int MX = BATCH * SXLEN;              // 3840
  const int MY = BATCH * SYLEN;              // 4352
  const long long DD = (long long)DMODEL * DMODEL;
  const long long SMEL = (long long)MY * DMODEL;
  const long long MXEL = (long long)MX * DMODEL;
  const long long FFEL = (long long)DMODEL * HFF;
  const long long PST  = (long long)MY * DMODEL;   // split-K partial stride

  // ---- workspace carve ----
  char* p = (char*)d_ws;
  auto alloc = [&](long long elems) -> bf16* {
    bf16* r = (bf16*)p; p += ((elems * 2 + 255) / 256) * 256; return r;
  };
  bf16* wt_attn = alloc(72 * DD);
  bf16* wt_f0   = alloc(12 * FFEL);
  bf16* wt_f1   = alloc(12 * FFEL);
  bf16* wt_fc   = alloc(32000LL * DMODEL);
  bf16* hx  = alloc(SMEL);
  bf16* hy  = alloc(SMEL);
  bf16* qb  = alloc(3 * SMEL);
  bf16* ao  = alloc(SMEL);
  bf16* h0  = alloc(SMEL);
  bf16* h1  = alloc(SMEL);
  bf16* mid = alloc((long long)MY * HFF);
  bf16* ckv = alloc(12 * MXEL);
  float* fp = (float*)alloc(2LL * MY * DMODEL * 2);  // 2 f32 split-K partials
  if ((size_t)(p - (char*)d_ws) > ws_size) return;

  bf16* wt_enc_attn = wt_attn;
  bf16* wt_dec_attn = wt_attn + 24 * DD;
  bf16* wt_enc_f0   = wt_f0;
  bf16* wt_dec_f0   = wt_f0 + 6 * FFEL;
  bf16* wt_enc_f1   = wt_f1;
  bf16* wt_dec_f1   = wt_f1 + 6 * FFEL;

  dim3 tb(32, 8);
  transpose_cast2<<<dim3(16, 16, 72), tb, 0, stream>>>(enc_attn_w, dec_attn_w, 24, wt_attn, DMODEL, DMODEL);
  transpose_cast2<<<dim3(64, 16, 12), tb, 0, stream>>>(enc_f0w, dec_f0w, 6, wt_f0, DMODEL, HFF);
  transpose_cast2<<<dim3(16, 64, 12), tb, 0, stream>>>(enc_f1w, dec_f1w, 6, wt_f1, HFF, DMODEL);
  transpose_cast2<<<dim3(1000, 16, 1), tb, 0, stream>>>(fc_w, fc_w, 1, wt_fc, DMODEL, 32000);

  embed2_k<<<MX + MY, 64, 0, stream>>>(x, y, emb_x, emb_y, hx, hy);

  // ---- encoder ----
  for (int i = 0; i < NLAYERS; ++i) {
    const bf16*  Wl = wt_enc_attn + (long long)i * 4 * DD;
    const float* Bl = enc_attn_b + (long long)i * 4 * DMODEL;
    const float* Lg = enc_ln + (size_t)i * 2048;
    gemm_t<0, 64, 64, 2, 2, 0, 1, 1, bf16><<<dim3(8, 60, 3), 256, 0, stream>>>(hx, Wl, Bl, qb,
        MX, DMODEL, DMODEL, DMODEL, DD, DMODEL, SMEL);
    attn_core<0><<<BATCH * NHEADS, 64, 0, stream>>>(qb, qb + SMEL, qb + 2 * SMEL, x, ao, SXLEN, SXLEN);
    // O-proj as split-K=2 -> f32 partials, then LN with residual
    gemm_t<0, 64, 64, 2, 2, 2, 0, 1, float><<<dim3(8, 60, 2), 256, 0, stream>>>(ao,
        Wl + 3 * DD, Bl + 3 * DMODEL, fp, MX, DMODEL, 256, DMODEL, 0, 0, PST);
    add_ln3_k<<<MX, 64, 0, stream>>>(hx, fp, PST, Bl + 3 * DMODEL, Lg, Lg + 512, h0);
    gemm_t<1, 128, 128, 2, 2, 0, 1, 1, bf16><<<dim3(16, 30, 1), 256, 0, stream>>>(h0,
        wt_enc_f0 + (long long)i * FFEL, enc_f0b + (long long)i * HFF, mid,
        MX, HFF, DMODEL, DMODEL, 0, 0, 0);
    gemm_t<0, 64, 64, 2, 2, 2, 0, 1, float><<<dim3(8, 60, 2), 256, 0, stream>>>(mid,
        wt_enc_f1 + (long long)i * FFEL, enc_f1b, fp,
        MX, DMODEL, 1024, HFF, 0, 0, PST);
    add_ln3_k<<<MX, 64, 0, stream>>>(h0, fp, PST,
        enc_f1b + (long long)i * DMODEL, Lg + 1024, Lg + 1536, hx);
  }

  // ---- all 6 decoder layers' cross K/V in one z=12 launch ----
  gemm_t<0, 64, 64, 2, 2, 1, 1, 1, bf16><<<dim3(8, 60, 12), 256, 0, stream>>>(hx, wt_dec_attn,
      dec_attn_b, ckv, MX, DMODEL, DMODEL, DMODEL, DD, DMODEL, MXEL);

  // ---- decoder ----
  for (int i = 0; i < NLAYERS; ++i) {
    const bf16*  Wl = wt_dec_attn + (long long)i * 8 * DD;
    const float* Bl = dec_attn_b + (long long)i * 8 * DMODEL;
    const float* Lg = dec_ln + (size_t)i * 3072;
    // self-attention
    gemm_t<0, 64, 64, 2, 2, 0, 1, 1, bf16><<<dim3(8, 68, 3), 256, 0, stream>>>(hy, Wl, Bl, qb,
        MY, DMODEL, DMODEL, DMODEL, DD, DMODEL, SMEL);
    attn_core<1><<<BATCH * NHEADS, 64, 0, stream>>>(qb, qb + SMEL, qb + 2 * SMEL, y, ao, SYLEN, SYLEN);
    gemm_t<0, 64, 64, 2, 2, 2, 0, 1, float><<<dim3(8, 68, 2), 256, 0, stream>>>(ao,
        Wl + 3 * DD, Bl + 3 * DMODEL, fp, MY, DMODEL, 256, DMODEL, 0, 0, PST);
    add_ln3_k<<<MY, 64, 0, stream>>>(hy, fp, PST, Bl + 3 * DMODEL, Lg, Lg + 512, h0);
    // cross-attention: q from h0; k/v precomputed in ckv
    gemm_t<0, 64, 64, 2, 2, 0, 1, 1, bf16><<<dim3(8, 68, 1), 256, 0, stream>>>(h0, Wl + 4 * DD, Bl + 4 * DMODEL, qb,
        MY, DMODEL, DMODEL, DMODEL, 0, 0, 0);
    attn_core<0><<<BATCH * NHEADS, 64, 0, stream>>>(qb, ckv + (long long)(2 * i) * MXEL,
        ckv + (long long)(2 * i + 1) * MXEL, x, ao, SYLEN, SXLEN);
    gemm_t<0, 64, 64, 2, 2, 2, 0, 1, float><<<dim3(8, 68, 2), 256, 0, stream>>>(ao,
        Wl + 7 * DD, Bl + 7 * DMODEL, fp, MY, DMODEL, 256, DMODEL, 0, 0, PST);
    add_ln3_k<<<MY, 64, 0, stream>>>(h0, fp, PST, Bl + 7 * DMODEL, Lg + 1024, Lg + 1536, h0);
    // FFN
    gemm_t<1, 128, 128, 2, 2, 0, 1, 1, bf16><<<dim3(16, 34, 1), 256, 0, stream>>>(h0,
        wt_dec_f0 + (long long)i * FFEL, dec_f0b + (long long)i * HFF, mid,
        MY, HFF, DMODEL, DMODEL, 0, 0, 0);
    gemm_t<0, 64, 64, 2, 2, 2, 0, 1, float><<<dim3(8, 68, 2), 256, 0, stream>>>(mid,
        wt_dec_f1 + (long long)i * FFEL, dec_f1b, fp,
        MY, DMODEL, 1024, HFF, 0, 0, PST);
    add_ln3_k<<<MY, 64, 0, stream>>>(h0, fp, PST,
        dec_f1b + (long long)i * DMODEL, Lg + 2048, Lg + 2560, hy);
  }

  // ---- final vocab projection (f32 out, 256x256 tile, 8 waves) ----
  gemm_t<0, 256, 256, 4, 2, 0, 1, 1, float><<<dim3(125, 17, 1), 512, 0, stream>>>(hy, wt_fc, fc_b,
      (float*)d_out, MY, 32000, DMODEL, DMODEL, 0, 0, 0);
}